// Round 1
// baseline (2093.391 us; speedup 1.0000x reference)
//
#include <hip/hip_runtime.h>
#include <hip/hip_bf16.h>
#include <stdint.h>

#define Bq  8
#define Sq  2048
#define Dq  768
#define Hq  3072
#define Oq  768
#define Eq  8
#define Mq  (Bq*Sq)            // 16384 tokens
#define LN_EPS 1e-5f

typedef unsigned short u16;
typedef __attribute__((ext_vector_type(4))) float f32x4;
typedef __attribute__((ext_vector_type(8))) __bf16 bf16x8;

static __device__ __forceinline__ u16 f2bf(float f) {
  __hip_bfloat16 h = __float2bfloat16(f);
  return __builtin_bit_cast(u16, h);
}

static __device__ __forceinline__ float gelu_f(float x) {
  // jax.nn.gelu approximate=True (tanh form)
  float u = 0.7978845608028654f * x * (1.0f + 0.044715f * x * x);
  float e = __expf(2.0f * u);
  float t = 1.0f - 2.0f / (e + 1.0f);   // tanh(u), NaN-free for e in [0,inf]
  return 0.5f * x * (1.0f + t);
}

typedef const __attribute__((address_space(1))) void* gas_t;
typedef __attribute__((address_space(3))) void* las_t;
static __device__ __forceinline__ void gload16(const void* g, void* l) {
  __builtin_amdgcn_global_load_lds((gas_t)g, (las_t)l, 16, 0, 0);
}

// ---------------- router: logits fp32, top-2, softmax -> dense w_all[M][E]
__global__ __launch_bounds__(256) void router_kernel(
    const float* __restrict__ x, const float* __restrict__ rw,
    const float* __restrict__ rb, float* __restrict__ w_all)
{
  int wid = threadIdx.x >> 6;
  int lane = threadIdx.x & 63;
  int token = blockIdx.x * 4 + wid;
  const float* xrow = x + (size_t)token * Dq;
  float acc[Eq];
#pragma unroll
  for (int e = 0; e < Eq; e++) acc[e] = 0.f;
#pragma unroll
  for (int i = 0; i < Dq / 64; i++) {
    int d = i * 64 + lane;
    float xv = xrow[d];
    const float4* rwp = (const float4*)(rw + (size_t)d * Eq);
    float4 r0 = rwp[0], r1 = rwp[1];
    acc[0] += xv * r0.x; acc[1] += xv * r0.y; acc[2] += xv * r0.z; acc[3] += xv * r0.w;
    acc[4] += xv * r1.x; acc[5] += xv * r1.y; acc[6] += xv * r1.z; acc[7] += xv * r1.w;
  }
#pragma unroll
  for (int e = 0; e < Eq; e++) {
    float v = acc[e];
#pragma unroll
    for (int off = 32; off; off >>= 1) v += __shfl_xor(v, off);
    acc[e] = v;
  }
  if (lane == 0) {
    float v1 = -1e30f, v2 = -1e30f; int i1 = 0, i2 = 0;
#pragma unroll
    for (int e = 0; e < Eq; e++) {
      float v = acc[e] + rb[e];
      if (v > v1)      { v2 = v1; i2 = i1; v1 = v; i1 = e; }
      else if (v > v2) { v2 = v;  i2 = e; }
    }
    float ex = expf(v2 - v1);
    float wa = 1.f / (1.f + ex);
    float wb = ex / (1.f + ex);
    float wr8[Eq];
#pragma unroll
    for (int e = 0; e < Eq; e++) wr8[e] = 0.f;
    wr8[i1] = wa; wr8[i2] = wb;
#pragma unroll
    for (int e = 0; e < Eq; e++) w_all[(size_t)token * Eq + e] = wr8[e];
  }
}

// ---------------- fp32 -> bf16 convert (vectorized)
__global__ __launch_bounds__(256) void cvt_x_kernel(
    const float* __restrict__ in, u16* __restrict__ out, int n4)
{
  int i = blockIdx.x * 256 + threadIdx.x;
  if (i >= n4) return;
  float4 v = ((const float4*)in)[i];
  ushort4 o;
  o.x = f2bf(v.x); o.y = f2bf(v.y); o.z = f2bf(v.z); o.w = f2bf(v.w);
  ((ushort4*)out)[i] = o;
}

// ---------------- transpose+convert: in[R][C] f32 -> out[C][R] bf16, per expert z
__global__ __launch_bounds__(256) void transpose_cvt(
    const float* __restrict__ in, u16* __restrict__ out, int R, int C)
{
  __shared__ float tile[32][33];
  int e = blockIdx.z;
  in  += (size_t)e * R * C;
  out += (size_t)e * R * C;
  int c0 = blockIdx.x * 32, r0 = blockIdx.y * 32;
  int tx = threadIdx.x & 31, ty = threadIdx.x >> 5;   // ty 0..7
#pragma unroll
  for (int rr = 0; rr < 32; rr += 8)
    tile[rr + ty][tx] = in[(size_t)(r0 + rr + ty) * C + c0 + tx];
  __syncthreads();
#pragma unroll
  for (int rr = 0; rr < 32; rr += 8)
    out[(size_t)(c0 + rr + ty) * R + r0 + tx] = f2bf(tile[tx][rr + ty]);
}

// ---------------- bf16 GEMM, 128x128 tile, BK=32, 4 waves (2x2), m97 structure
// A [rows][K] bf16 row-major; BT [N][K] bf16 row-major; C = A @ BT^T
// EPI 0: Hout[r][c] = bf16(gelu(acc + bias[c]))
// EPI 1: out[(m_base+r)*Oq + c] += (acc + bias[c]) * w_all[(m_base+r)*Eq]  (w_all pre-offset by e)
template<int EPI>
__global__ __launch_bounds__(256) void gemm_kernel(
    const u16* __restrict__ A, const u16* __restrict__ BT,
    int K, int N, const float* __restrict__ bias,
    u16* __restrict__ Hout, float* __restrict__ out,
    const float* __restrict__ w_all, int m_base)
{
  __shared__ u16 As[128 * 32];
  __shared__ u16 Bs[128 * 32];
  const int tid  = threadIdx.x;
  const int lane = tid & 63;
  const int wid  = tid >> 6;
  const int wr   = wid >> 1, wc = wid & 1;
  const int lrow = lane & 15, kgrp = lane >> 4;

  const int m0 = blockIdx.x * 128;
  const int n0 = blockIdx.y * 128;

  f32x4 acc[4][4];
#pragma unroll
  for (int m = 0; m < 4; m++)
#pragma unroll
    for (int n = 0; n < 4; n++) acc[m][n] = (f32x4){0.f, 0.f, 0.f, 0.f};

  const u16* gA = A  + (size_t)(m0 + (tid >> 2)) * K + (tid & 3) * 8;
  const u16* gB = BT + (size_t)(n0 + (tid >> 2)) * K + (tid & 3) * 8;
  u16* lA = &As[tid * 8];
  u16* lB = &Bs[tid * 8];
  const size_t rowskip = (size_t)64 * K;

  for (int k0 = 0; k0 < K; k0 += 32) {
    gload16(gA,           lA);
    gload16(gA + rowskip, lA + 2048);
    gload16(gB,           lB);
    gload16(gB + rowskip, lB + 2048);
    gA += 32; gB += 32;
    __syncthreads();
    bf16x8 a[4], b[4];
#pragma unroll
    for (int m = 0; m < 4; m++)
      a[m] = *(const bf16x8*)&As[(wr * 64 + m * 16 + lrow) * 32 + kgrp * 8];
#pragma unroll
    for (int n = 0; n < 4; n++)
      b[n] = *(const bf16x8*)&Bs[(wc * 64 + n * 16 + lrow) * 32 + kgrp * 8];
#pragma unroll
    for (int m = 0; m < 4; m++)
#pragma unroll
      for (int n = 0; n < 4; n++)
        acc[m][n] = __builtin_amdgcn_mfma_f32_16x16x32_bf16(a[m], b[n], acc[m][n], 0, 0, 0);
    __syncthreads();
  }

  const int rbase = m0 + wr * 64;
  const int cbase = n0 + wc * 64;
  if (EPI == 0) {
#pragma unroll
    for (int n = 0; n < 4; n++) {
      int c = cbase + n * 16 + lrow;
      float bv = bias[c];
#pragma unroll
      for (int m = 0; m < 4; m++)
#pragma unroll
        for (int j = 0; j < 4; j++) {
          int r = rbase + m * 16 + kgrp * 4 + j;
          float v = acc[m][n][j] + bv;
          Hout[(size_t)r * N + c] = f2bf(gelu_f(v));
        }
    }
  } else {
#pragma unroll
    for (int m = 0; m < 4; m++)
#pragma unroll
      for (int j = 0; j < 4; j++) {
        int r = rbase + m * 16 + kgrp * 4 + j;
        float w = w_all[(size_t)(m_base + r) * Eq];
        if (w != 0.f) {
          float* orow = out + (size_t)(m_base + r) * Oq;
#pragma unroll
          for (int n = 0; n < 4; n++) {
            int c = cbase + n * 16 + lrow;
            orow[c] += (acc[m][n][j] + bias[c]) * w;
          }
        }
      }
  }
}

// ---------------- in-place LayerNorm, one wave per row
__global__ __launch_bounds__(256) void ln_kernel(
    float* __restrict__ io, const float* __restrict__ g, const float* __restrict__ b)
{
  int wid = threadIdx.x >> 6, lane = threadIdx.x & 63;
  int row = blockIdx.x * 4 + wid;
  float* p = io + (size_t)row * Oq;
  float v[Oq / 64];
  float s = 0.f;
#pragma unroll
  for (int i = 0; i < Oq / 64; i++) { v[i] = p[lane + i * 64]; s += v[i]; }
#pragma unroll
  for (int off = 32; off; off >>= 1) s += __shfl_xor(s, off);
  float mu = s * (1.0f / Oq);
  float q = 0.f;
#pragma unroll
  for (int i = 0; i < Oq / 64; i++) { float d = v[i] - mu; q += d * d; }
#pragma unroll
  for (int off = 32; off; off >>= 1) q += __shfl_xor(q, off);
  float inv = rsqrtf(q * (1.0f / Oq) + LN_EPS);
#pragma unroll
  for (int i = 0; i < Oq / 64; i++) {
    int c = lane + i * 64;
    p[c] = (v[i] - mu) * inv * g[c] + b[c];
  }
}

extern "C" void kernel_launch(void* const* d_in, const int* in_sizes, int n_in,
                              void* d_out, int out_size, void* d_ws, size_t ws_size,
                              hipStream_t stream)
{
  const float* x    = (const float*)d_in[0];
  const float* rw   = (const float*)d_in[1];
  const float* rb   = (const float*)d_in[2];
  const float* w1   = (const float*)d_in[3];
  const float* b1   = (const float*)d_in[4];
  const float* w2   = (const float*)d_in[5];
  const float* b2   = (const float*)d_in[6];
  const float* ln_g = (const float*)d_in[7];
  const float* ln_b = (const float*)d_in[8];
  float* out = (float*)d_out;

  char* ws = (char*)d_ws;
  size_t off = 0;
  auto alloc = [&](size_t bytes) {
    void* p = ws + off;
    off += (bytes + 255) & ~(size_t)255;
    return p;
  };
  float* w_all = (float*)alloc((size_t)Mq * Eq * 4);
  u16* Xbf = (u16*)alloc((size_t)Mq * Dq * 2);
  u16* W1T = (u16*)alloc((size_t)Eq * Dq * Hq * 2);
  u16* W2T = (u16*)alloc((size_t)Eq * Hq * Oq * 2);
  size_t remain = (ws_size > off) ? ws_size - off : 0;
  long long mr = (long long)(remain / ((size_t)Hq * 2));
  mr &= ~127LL;
  if (mr > Mq) mr = Mq;
  if (mr < 128) mr = 128;   // require at least one row-tile of scratch
  int max_rows = (int)mr;
  u16* Hbuf = (u16*)alloc((size_t)max_rows * Hq * 2);

  hipMemsetAsync(d_out, 0, (size_t)Mq * Oq * 4, stream);
  router_kernel<<<Mq / 4, 256, 0, stream>>>(x, rw, rb, w_all);
  cvt_x_kernel<<<(Mq * Dq / 4 + 255) / 256, 256, 0, stream>>>(x, Xbf, Mq * Dq / 4);
  transpose_cvt<<<dim3(Hq / 32, Dq / 32, Eq), 256, 0, stream>>>(w1, W1T, Dq, Hq);
  transpose_cvt<<<dim3(Oq / 32, Hq / 32, Eq), 256, 0, stream>>>(w2, W2T, Hq, Oq);

  for (int mb = 0; mb < Mq; mb += max_rows) {
    int rows = (Mq - mb < max_rows) ? (Mq - mb) : max_rows;
    for (int e = 0; e < Eq; e++) {
      gemm_kernel<0><<<dim3(rows / 128, Hq / 128), 256, 0, stream>>>(
          Xbf + (size_t)mb * Dq, W1T + (size_t)e * Dq * Hq, Dq, Hq,
          b1 + (size_t)e * Hq, Hbuf, nullptr, nullptr, 0);
      gemm_kernel<1><<<dim3(rows / 128, Oq / 128), 256, 0, stream>>>(
          Hbuf, W2T + (size_t)e * Hq * Oq, Hq, Oq,
          b2 + (size_t)e * Oq, nullptr, out, w_all + e, mb);
    }
  }
  ln_kernel<<<Mq / 4, 256, 0, stream>>>(out, ln_g, ln_b);
}

// Round 2
// 1320.876 us; speedup vs baseline: 1.5849x; 1.5849x over previous
//
#include <hip/hip_runtime.h>
#include <hip/hip_bf16.h>
#include <stdint.h>

#define Bq  8
#define Sq  2048
#define Dq  768
#define Hq  3072
#define Oq  768
#define Eq  8
#define Mq  (Bq*Sq)            // 16384 tokens
#define LN_EPS 1e-5f
#define MAX_TILES (2*Mq/128 + 16)   // 272 worst-case padded 128-row tiles

typedef unsigned short u16;
typedef __attribute__((ext_vector_type(4))) float f32x4;
typedef __attribute__((ext_vector_type(8))) __bf16 bf16x8;

static __device__ __forceinline__ u16 f2bf(float f) {
  __hip_bfloat16 h = __float2bfloat16(f);
  return __builtin_bit_cast(u16, h);
}

static __device__ __forceinline__ float gelu_f(float x) {
  // jax.nn.gelu approximate=True (tanh form)
  float u = 0.7978845608028654f * x * (1.0f + 0.044715f * x * x);
  float e = __expf(2.0f * u);
  float t = 1.0f - 2.0f / (e + 1.0f);   // tanh(u), NaN-free
  return 0.5f * x * (1.0f + t);
}

typedef const __attribute__((address_space(1))) void* gas_t;
typedef __attribute__((address_space(3))) void* las_t;
static __device__ __forceinline__ void gload16(const void* g, void* l) {
  __builtin_amdgcn_global_load_lds((gas_t)g, (las_t)l, 16, 0, 0);
}

// ---------------- router: logits fp32, top-2, softmax; append to 16 segment
// lists: seg = rank*8 + expert. seg_tok[seg*Mq + pos] = token, seg_wgt = weight.
__global__ __launch_bounds__(256) void router_kernel(
    const float* __restrict__ x, const float* __restrict__ rw,
    const float* __restrict__ rb, int* __restrict__ cnt,
    int* __restrict__ seg_tok, float* __restrict__ seg_wgt)
{
  int wid = threadIdx.x >> 6;
  int lane = threadIdx.x & 63;
  int token = blockIdx.x * 4 + wid;
  const float* xrow = x + (size_t)token * Dq;
  float acc[Eq];
#pragma unroll
  for (int e = 0; e < Eq; e++) acc[e] = 0.f;
#pragma unroll
  for (int i = 0; i < Dq / 64; i++) {
    int d = i * 64 + lane;
    float xv = xrow[d];
    const float4* rwp = (const float4*)(rw + (size_t)d * Eq);
    float4 r0 = rwp[0], r1 = rwp[1];
    acc[0] += xv * r0.x; acc[1] += xv * r0.y; acc[2] += xv * r0.z; acc[3] += xv * r0.w;
    acc[4] += xv * r1.x; acc[5] += xv * r1.y; acc[6] += xv * r1.z; acc[7] += xv * r1.w;
  }
#pragma unroll
  for (int e = 0; e < Eq; e++) {
    float v = acc[e];
#pragma unroll
    for (int off = 32; off; off >>= 1) v += __shfl_xor(v, off);
    acc[e] = v;
  }
  if (lane == 0) {
    float v1 = -1e30f, v2 = -1e30f; int i1 = 0, i2 = 0;
#pragma unroll
    for (int e = 0; e < Eq; e++) {
      float v = acc[e] + rb[e];
      if (v > v1)      { v2 = v1; i2 = i1; v1 = v; i1 = e; }
      else if (v > v2) { v2 = v;  i2 = e; }
    }
    float ex = expf(v2 - v1);
    float wa = 1.f / (1.f + ex);
    float wb = ex / (1.f + ex);
    int s0 = i1;            // rank 0
    int s1 = 8 + i2;        // rank 1
    int p0 = atomicAdd(&cnt[s0], 1);
    seg_tok[(size_t)s0 * Mq + p0] = token;
    seg_wgt[(size_t)s0 * Mq + p0] = wa;
    int p1 = atomicAdd(&cnt[s1], 1);
    seg_tok[(size_t)s1 * Mq + p1] = token;
    seg_wgt[(size_t)s1 * Mq + p1] = wb;
  }
}

// ---------------- tile prefix over 16 segments (1 thread)
__global__ void prefix_kernel(const int* __restrict__ cnt, int* __restrict__ prefix)
{
  if (threadIdx.x == 0 && blockIdx.x == 0) {
    int t = 0;
#pragma unroll
    for (int s = 0; s < 16; s++) { prefix[s] = t; t += (cnt[s] + 127) >> 7; }
    prefix[16] = t;
  }
}

// ---------------- fp32 -> bf16 convert (vectorized)
__global__ __launch_bounds__(256) void cvt_x_kernel(
    const float* __restrict__ in, u16* __restrict__ out, int n4)
{
  int i = blockIdx.x * 256 + threadIdx.x;
  if (i >= n4) return;
  float4 v = ((const float4*)in)[i];
  ushort4 o;
  o.x = f2bf(v.x); o.y = f2bf(v.y); o.z = f2bf(v.z); o.w = f2bf(v.w);
  ((ushort4*)out)[i] = o;
}

// ---------------- transpose+convert: in[R][C] f32 -> out[C][R] bf16, per expert z
__global__ __launch_bounds__(256) void transpose_cvt(
    const float* __restrict__ in, u16* __restrict__ out, int R, int C)
{
  __shared__ float tile[32][33];
  int e = blockIdx.z;
  in  += (size_t)e * R * C;
  out += (size_t)e * R * C;
  int c0 = blockIdx.x * 32, r0 = blockIdx.y * 32;
  int tx = threadIdx.x & 31, ty = threadIdx.x >> 5;   // ty 0..7
#pragma unroll
  for (int rr = 0; rr < 32; rr += 8)
    tile[rr + ty][tx] = in[(size_t)(r0 + rr + ty) * C + c0 + tx];
  __syncthreads();
#pragma unroll
  for (int rr = 0; rr < 32; rr += 8)
    out[(size_t)(c0 + rr + ty) * R + r0 + tx] = f2bf(tile[tx][rr + ty]);
}

// ---------------- grouped bf16 GEMM over padded 128-row tiles
// EPI 0 (GEMM1): A = Xbf[M][D] gathered via seg_tok; B = W1T[e][H][D];
//                Hout[localslot][Hq] = bf16(gelu(acc + b1[e][c]))
// EPI 1 (GEMM2): A = Hbuf[localslot][Hq]; B = W2T[e][O][H];
//                rank-0: out[token][c]  = (acc + b2[e][c]) * w
//                rank-1: out[token][c] += (acc + b2[e][c]) * w
template<int EPI>
__global__ __launch_bounds__(256) void moe_gemm(
    const u16* __restrict__ A, const u16* __restrict__ W,
    const float* __restrict__ bias,
    u16* __restrict__ Hout, float* __restrict__ out,
    const int* __restrict__ cnt, const int* __restrict__ prefix,
    const int* __restrict__ seg_tok, const float* __restrict__ seg_wgt,
    int K, int N, int tile_lo, int klass)
{
  const int t = tile_lo + (int)blockIdx.x;
  const int total = prefix[16];
  if (t >= total) return;
  int seg = 0;
#pragma unroll
  for (int s = 1; s < 16; s++) if (prefix[s] <= t) seg = s;
  if (EPI == 1 && (seg >> 3) != klass) return;
  const int e = seg & 7;
  const int segcnt = cnt[seg];
  const int ti = t - prefix[seg];       // tile within segment
  const int lt = t - tile_lo;           // local tile (Hbuf)

  __shared__ u16 As[128 * 32];
  __shared__ u16 Bs[128 * 32];
  const int tid  = threadIdx.x;
  const int lane = tid & 63;
  const int wid  = tid >> 6;
  const int wr   = wid >> 1, wc = wid & 1;
  const int lrow = lane & 15, kgrp = lane >> 4;
  const int n0 = blockIdx.y * 128;

  f32x4 acc[4][4];
#pragma unroll
  for (int m = 0; m < 4; m++)
#pragma unroll
    for (int n = 0; n < 4; n++) acc[m][n] = (f32x4){0.f, 0.f, 0.f, 0.f};

  // staging addresses: thread stages rows r0 and r0+64 at k-chunk (tid&3)*8
  const int r0 = tid >> 2, kc = (tid & 3) * 8;
  const u16 *gA0, *gA1;
  if (EPI == 0) {
    int i0 = ti * 128 + r0, i1 = i0 + 64;
    int tok0 = (i0 < segcnt) ? seg_tok[(size_t)seg * Mq + i0] : 0;
    int tok1 = (i1 < segcnt) ? seg_tok[(size_t)seg * Mq + i1] : 0;
    gA0 = A + (size_t)tok0 * K + kc;
    gA1 = A + (size_t)tok1 * K + kc;
  } else {
    gA0 = A + (size_t)(lt * 128 + r0) * K + kc;
    gA1 = gA0 + (size_t)64 * K;
  }
  const u16* gB = W + (size_t)e * K * N + (size_t)(n0 + r0) * K + kc;
  u16* lA = &As[tid * 8];
  u16* lB = &Bs[tid * 8];
  const size_t rowskipB = (size_t)64 * K;

  for (int k0 = 0; k0 < K; k0 += 32) {
    gload16(gA0, lA);
    gload16(gA1, lA + 2048);
    gload16(gB,            lB);
    gload16(gB + rowskipB, lB + 2048);
    gA0 += 32; gA1 += 32; gB += 32;
    __syncthreads();
    bf16x8 a[4], b[4];
#pragma unroll
    for (int m = 0; m < 4; m++)
      a[m] = *(const bf16x8*)&As[(wr * 64 + m * 16 + lrow) * 32 + kgrp * 8];
#pragma unroll
    for (int n = 0; n < 4; n++)
      b[n] = *(const bf16x8*)&Bs[(wc * 64 + n * 16 + lrow) * 32 + kgrp * 8];
#pragma unroll
    for (int m = 0; m < 4; m++)
#pragma unroll
      for (int n = 0; n < 4; n++)
        acc[m][n] = __builtin_amdgcn_mfma_f32_16x16x32_bf16(a[m], b[n], acc[m][n], 0, 0, 0);
    __syncthreads();
  }

  const int rbase = wr * 64;
  const int cbase = n0 + wc * 64;
  if (EPI == 0) {
#pragma unroll
    for (int n = 0; n < 4; n++) {
      int c = cbase + n * 16 + lrow;
      float bv = bias[(size_t)e * N + c];
#pragma unroll
      for (int m = 0; m < 4; m++)
#pragma unroll
        for (int j = 0; j < 4; j++) {
          int r = rbase + m * 16 + kgrp * 4 + j;
          float v = acc[m][n][j] + bv;
          Hout[(size_t)(lt * 128 + r) * N + c] = f2bf(gelu_f(v));
        }
    }
  } else {
#pragma unroll
    for (int m = 0; m < 4; m++)
#pragma unroll
      for (int j = 0; j < 4; j++) {
        int r = rbase + m * 16 + kgrp * 4 + j;
        int i = ti * 128 + r;
        if (i < segcnt) {
          int token = seg_tok[(size_t)seg * Mq + i];
          float w = seg_wgt[(size_t)seg * Mq + i];
          float* orow = out + (size_t)token * Oq;
#pragma unroll
          for (int n = 0; n < 4; n++) {
            int c = cbase + n * 16 + lrow;
            float v = (acc[m][n][j] + bias[(size_t)e * N + c]) * w;
            if (klass == 0) orow[c] = v;
            else            orow[c] += v;
          }
        }
      }
  }
}

// ---------------- in-place LayerNorm, one wave per row
__global__ __launch_bounds__(256) void ln_kernel(
    float* __restrict__ io, const float* __restrict__ g, const float* __restrict__ b)
{
  int wid = threadIdx.x >> 6, lane = threadIdx.x & 63;
  int row = blockIdx.x * 4 + wid;
  float* p = io + (size_t)row * Oq;
  float v[Oq / 64];
  float s = 0.f;
#pragma unroll
  for (int i = 0; i < Oq / 64; i++) { v[i] = p[lane + i * 64]; s += v[i]; }
#pragma unroll
  for (int off = 32; off; off >>= 1) s += __shfl_xor(s, off);
  float mu = s * (1.0f / Oq);
  float q = 0.f;
#pragma unroll
  for (int i = 0; i < Oq / 64; i++) { float d = v[i] - mu; q += d * d; }
#pragma unroll
  for (int off = 32; off; off >>= 1) q += __shfl_xor(q, off);
  float inv = rsqrtf(q * (1.0f / Oq) + LN_EPS);
#pragma unroll
  for (int i = 0; i < Oq / 64; i++) {
    int c = lane + i * 64;
    p[c] = (v[i] - mu) * inv * g[c] + b[c];
  }
}

extern "C" void kernel_launch(void* const* d_in, const int* in_sizes, int n_in,
                              void* d_out, int out_size, void* d_ws, size_t ws_size,
                              hipStream_t stream)
{
  const float* x    = (const float*)d_in[0];
  const float* rw   = (const float*)d_in[1];
  const float* rb   = (const float*)d_in[2];
  const float* w1   = (const float*)d_in[3];
  const float* b1   = (const float*)d_in[4];
  const float* w2   = (const float*)d_in[5];
  const float* b2   = (const float*)d_in[6];
  const float* ln_g = (const float*)d_in[7];
  const float* ln_b = (const float*)d_in[8];
  float* out = (float*)d_out;

  char* ws = (char*)d_ws;
  size_t off = 0;
  auto alloc = [&](size_t bytes) {
    void* p = ws + off;
    off += (bytes + 255) & ~(size_t)255;
    return p;
  };
  int*   cnt     = (int*)alloc(16 * 4);
  int*   prefix  = (int*)alloc(17 * 4);
  int*   seg_tok = (int*)alloc((size_t)16 * Mq * 4);
  float* seg_wgt = (float*)alloc((size_t)16 * Mq * 4);
  u16* Xbf = (u16*)alloc((size_t)Mq * Dq * 2);
  u16* W1T = (u16*)alloc((size_t)Eq * Dq * Hq * 2);
  u16* W2T = (u16*)alloc((size_t)Eq * Hq * Oq * 2);

  size_t remain = (ws_size > off) ? ws_size - off : 0;
  size_t tile_bytes = (size_t)128 * Hq * 2;   // 768 KB per slot-tile
  long long wt = (long long)(remain / tile_bytes);
  if (wt > MAX_TILES) wt = MAX_TILES;
  if (wt < 1) wt = 1;
  int WT = (int)wt;
  u16* Hbuf = (u16*)alloc((size_t)WT * tile_bytes);

  hipMemsetAsync(cnt, 0, 16 * 4, stream);
  router_kernel<<<Mq / 4, 256, 0, stream>>>(x, rw, rb, cnt, seg_tok, seg_wgt);
  prefix_kernel<<<1, 64, 0, stream>>>(cnt, prefix);
  cvt_x_kernel<<<(Mq * Dq / 4 + 255) / 256, 256, 0, stream>>>(x, Xbf, Mq * Dq / 4);
  transpose_cvt<<<dim3(Hq / 32, Dq / 32, Eq), 256, 0, stream>>>(w1, W1T, Dq, Hq);
  transpose_cvt<<<dim3(Oq / 32, Hq / 32, Eq), 256, 0, stream>>>(w2, W2T, Hq, Oq);

  for (int tl = 0; tl < MAX_TILES; tl += WT) {
    int gx = MAX_TILES - tl; if (gx > WT) gx = WT;
    moe_gemm<0><<<dim3(gx, Hq / 128), 256, 0, stream>>>(
        Xbf, W1T, b1, Hbuf, nullptr, cnt, prefix, seg_tok, seg_wgt,
        Dq, Hq, tl, 0);
    moe_gemm<1><<<dim3(gx, Oq / 128), 256, 0, stream>>>(
        Hbuf, W2T, b2, nullptr, out, cnt, prefix, seg_tok, seg_wgt,
        Hq, Oq, tl, 0);
    moe_gemm<1><<<dim3(gx, Oq / 128), 256, 0, stream>>>(
        Hbuf, W2T, b2, nullptr, out, cnt, prefix, seg_tok, seg_wgt,
        Hq, Oq, tl, 1);
  }
  ln_kernel<<<Mq / 4, 256, 0, stream>>>(out, ln_g, ln_b);
}

// Round 3
// 1306.823 us; speedup vs baseline: 1.6019x; 1.0108x over previous
//
#include <hip/hip_runtime.h>
#include <hip/hip_bf16.h>
#include <stdint.h>

#define Bq  8
#define Sq  2048
#define Dq  768
#define Hq  3072
#define Oq  768
#define Eq  8
#define Mq  (Bq*Sq)            // 16384 tokens
#define LN_EPS 1e-5f
#define MAX_TILES (2*Mq/128 + 16)   // 272 worst-case padded 128-row tiles

typedef unsigned short u16;
typedef __attribute__((ext_vector_type(4))) float f32x4;
typedef __attribute__((ext_vector_type(8))) __bf16 bf16x8;

static __device__ __forceinline__ u16 f2bf(float f) {
  __hip_bfloat16 h = __float2bfloat16(f);
  return __builtin_bit_cast(u16, h);
}

static __device__ __forceinline__ float gelu_f(float x) {
  // jax.nn.gelu approximate=True (tanh form)
  float u = 0.7978845608028654f * x * (1.0f + 0.044715f * x * x);
  float e = __expf(2.0f * u);
  float t = 1.0f - 2.0f / (e + 1.0f);   // tanh(u), NaN-free
  return 0.5f * x * (1.0f + t);
}

typedef const __attribute__((address_space(1))) void* gas_t;
typedef __attribute__((address_space(3))) void* las_t;
static __device__ __forceinline__ void gload16(const void* g, void* l) {
  __builtin_amdgcn_global_load_lds((gas_t)g, (las_t)l, 16, 0, 0);
}

// ---------------- fused router + fp32->bf16 convert.
// One wave per token row. Lanes read float4 of x (coalesced, 3 iters),
// write bf16 row, and accumulate 8 expert logits vs LDS-staged rw^T.
__global__ __launch_bounds__(256) void router_cvt_kernel(
    const float* __restrict__ x, const float* __restrict__ rw,
    const float* __restrict__ rb, u16* __restrict__ Xbf,
    int* __restrict__ cnt, int* __restrict__ seg_tok, float* __restrict__ seg_wgt)
{
  __shared__ float rwT[Eq * Dq];      // 24 KB: rwT[e][d]
  for (int i = threadIdx.x; i < Eq * Dq; i += 256)
    rwT[(i & 7) * Dq + (i >> 3)] = rw[i];
  __syncthreads();

  int wid = threadIdx.x >> 6;
  int lane = threadIdx.x & 63;
  int token = blockIdx.x * 4 + wid;
  const float4* xrow = (const float4*)(x + (size_t)token * Dq);
  ushort4* orow = (ushort4*)(Xbf + (size_t)token * Dq);

  float acc[Eq];
#pragma unroll
  for (int e = 0; e < Eq; e++) acc[e] = 0.f;

#pragma unroll
  for (int it = 0; it < Dq / 256; it++) {
    int d4 = it * 64 + lane;                 // float4 index within row
    float4 xv = xrow[d4];
    ushort4 o;
    o.x = f2bf(xv.x); o.y = f2bf(xv.y); o.z = f2bf(xv.z); o.w = f2bf(xv.w);
    orow[d4] = o;
    int d = d4 * 4;
#pragma unroll
    for (int e = 0; e < Eq; e++) {
      float4 wv = *(const float4*)&rwT[e * Dq + d];
      acc[e] += xv.x * wv.x + xv.y * wv.y + xv.z * wv.z + xv.w * wv.w;
    }
  }
#pragma unroll
  for (int e = 0; e < Eq; e++) {
    float v = acc[e];
#pragma unroll
    for (int off = 32; off; off >>= 1) v += __shfl_xor(v, off);
    acc[e] = v;
  }
  if (lane == 0) {
    float v1 = -1e30f, v2 = -1e30f; int i1 = 0, i2 = 0;
#pragma unroll
    for (int e = 0; e < Eq; e++) {
      float v = acc[e] + rb[e];
      if (v > v1)      { v2 = v1; i2 = i1; v1 = v; i1 = e; }
      else if (v > v2) { v2 = v;  i2 = e; }
    }
    float ex = expf(v2 - v1);
    float wa = 1.f / (1.f + ex);
    float wb = ex / (1.f + ex);
    int s0 = i1;            // rank 0
    int s1 = 8 + i2;        // rank 1
    int p0 = atomicAdd(&cnt[s0], 1);
    seg_tok[(size_t)s0 * Mq + p0] = token;
    seg_wgt[(size_t)s0 * Mq + p0] = wa;
    int p1 = atomicAdd(&cnt[s1], 1);
    seg_tok[(size_t)s1 * Mq + p1] = token;
    seg_wgt[(size_t)s1 * Mq + p1] = wb;
  }
}

// ---------------- tile prefix over 16 segments (1 thread)
__global__ void prefix_kernel(const int* __restrict__ cnt, int* __restrict__ prefix)
{
  if (threadIdx.x == 0 && blockIdx.x == 0) {
    int t = 0;
#pragma unroll
    for (int s = 0; s < 16; s++) { prefix[s] = t; t += (cnt[s] + 127) >> 7; }
    prefix[16] = t;
  }
}

// ---------------- transpose+convert: in[R][C] f32 -> out[C][R] bf16, per expert z
__global__ __launch_bounds__(256) void transpose_cvt(
    const float* __restrict__ in, u16* __restrict__ out, int R, int C)
{
  __shared__ float tile[32][33];
  int e = blockIdx.z;
  in  += (size_t)e * R * C;
  out += (size_t)e * R * C;
  int c0 = blockIdx.x * 32, r0 = blockIdx.y * 32;
  int tx = threadIdx.x & 31, ty = threadIdx.x >> 5;   // ty 0..7
#pragma unroll
  for (int rr = 0; rr < 32; rr += 8)
    tile[rr + ty][tx] = in[(size_t)(r0 + rr + ty) * C + c0 + tx];
  __syncthreads();
#pragma unroll
  for (int rr = 0; rr < 32; rr += 8)
    out[(size_t)(c0 + rr + ty) * R + r0 + tx] = f2bf(tile[tx][rr + ty]);
}

// ---------------- grouped bf16 GEMM over padded 128-row tiles
// EPI 0 (GEMM1): A = Xbf[M][D] gathered via seg_tok; B = W1T[e][H][D];
//                Hout[localslot][Hq] = bf16(gelu(acc + b1[e][c]))
// EPI 1 (GEMM2): A = Hbuf[localslot][Hq]; B = W2T[e][O][H];
//                rank-0: out[token][c]  = (acc + b2[e][c]) * w
//                rank-1: out[token][c] += (acc + b2[e][c]) * w
template<int EPI>
__global__ __launch_bounds__(256) void moe_gemm(
    const u16* __restrict__ A, const u16* __restrict__ W,
    const float* __restrict__ bias,
    u16* __restrict__ Hout, float* __restrict__ out,
    const int* __restrict__ cnt, const int* __restrict__ prefix,
    const int* __restrict__ seg_tok, const float* __restrict__ seg_wgt,
    int K, int N, int tile_lo, int klass)
{
  const int t = tile_lo + (int)blockIdx.x;
  const int total = prefix[16];
  if (t >= total) return;
  int seg = 0;
#pragma unroll
  for (int s = 1; s < 16; s++) if (prefix[s] <= t) seg = s;
  if (EPI == 1 && (seg >> 3) != klass) return;
  const int e = seg & 7;
  const int segcnt = cnt[seg];
  const int ti = t - prefix[seg];       // tile within segment
  const int lt = t - tile_lo;           // local tile (Hbuf)

  __shared__ u16 As[128 * 32];
  __shared__ u16 Bs[128 * 32];
  const int tid  = threadIdx.x;
  const int lane = tid & 63;
  const int wid  = tid >> 6;
  const int wr   = wid >> 1, wc = wid & 1;
  const int lrow = lane & 15, kgrp = lane >> 4;
  const int n0 = blockIdx.y * 128;

  f32x4 acc[4][4];
#pragma unroll
  for (int m = 0; m < 4; m++)
#pragma unroll
    for (int n = 0; n < 4; n++) acc[m][n] = (f32x4){0.f, 0.f, 0.f, 0.f};

  // staging addresses: thread stages rows r0 and r0+64 at k-chunk (tid&3)*8
  const int r0 = tid >> 2, kc = (tid & 3) * 8;
  const u16 *gA0, *gA1;
  if (EPI == 0) {
    int i0 = ti * 128 + r0, i1 = i0 + 64;
    int tok0 = (i0 < segcnt) ? seg_tok[(size_t)seg * Mq + i0] : 0;
    int tok1 = (i1 < segcnt) ? seg_tok[(size_t)seg * Mq + i1] : 0;
    gA0 = A + (size_t)tok0 * K + kc;
    gA1 = A + (size_t)tok1 * K + kc;
  } else {
    gA0 = A + (size_t)(lt * 128 + r0) * K + kc;
    gA1 = gA0 + (size_t)64 * K;
  }
  const u16* gB = W + (size_t)e * K * N + (size_t)(n0 + r0) * K + kc;
  u16* lA = &As[tid * 8];
  u16* lB = &Bs[tid * 8];
  const size_t rowskipB = (size_t)64 * K;

  for (int k0 = 0; k0 < K; k0 += 32) {
    gload16(gA0, lA);
    gload16(gA1, lA + 2048);
    gload16(gB,            lB);
    gload16(gB + rowskipB, lB + 2048);
    gA0 += 32; gA1 += 32; gB += 32;
    __syncthreads();
    bf16x8 a[4], b[4];
#pragma unroll
    for (int m = 0; m < 4; m++)
      a[m] = *(const bf16x8*)&As[(wr * 64 + m * 16 + lrow) * 32 + kgrp * 8];
#pragma unroll
    for (int n = 0; n < 4; n++)
      b[n] = *(const bf16x8*)&Bs[(wc * 64 + n * 16 + lrow) * 32 + kgrp * 8];
#pragma unroll
    for (int m = 0; m < 4; m++)
#pragma unroll
      for (int n = 0; n < 4; n++)
        acc[m][n] = __builtin_amdgcn_mfma_f32_16x16x32_bf16(a[m], b[n], acc[m][n], 0, 0, 0);
    __syncthreads();
  }

  const int rbase = wr * 64;
  const int cbase = n0 + wc * 64;
  if (EPI == 0) {
#pragma unroll
    for (int n = 0; n < 4; n++) {
      int c = cbase + n * 16 + lrow;
      float bv = bias[(size_t)e * N + c];
#pragma unroll
      for (int m = 0; m < 4; m++)
#pragma unroll
        for (int j = 0; j < 4; j++) {
          int r = rbase + m * 16 + kgrp * 4 + j;
          float v = acc[m][n][j] + bv;
          Hout[(size_t)(lt * 128 + r) * N + c] = f2bf(gelu_f(v));
        }
    }
  } else {
#pragma unroll
    for (int m = 0; m < 4; m++)
#pragma unroll
      for (int j = 0; j < 4; j++) {
        int r = rbase + m * 16 + kgrp * 4 + j;
        int i = ti * 128 + r;
        if (i < segcnt) {
          int token = seg_tok[(size_t)seg * Mq + i];
          float w = seg_wgt[(size_t)seg * Mq + i];
          float* orow = out + (size_t)token * Oq;
#pragma unroll
          for (int n = 0; n < 4; n++) {
            int c = cbase + n * 16 + lrow;
            float v = (acc[m][n][j] + bias[(size_t)e * N + c]) * w;
            if (klass == 0) orow[c] = v;
            else            orow[c] += v;
          }
        }
      }
  }
}

// ---------------- in-place LayerNorm, one wave per row
__global__ __launch_bounds__(256) void ln_kernel(
    float* __restrict__ io, const float* __restrict__ g, const float* __restrict__ b)
{
  int wid = threadIdx.x >> 6, lane = threadIdx.x & 63;
  int row = blockIdx.x * 4 + wid;
  float* p = io + (size_t)row * Oq;
  float v[Oq / 64];
  float s = 0.f;
#pragma unroll
  for (int i = 0; i < Oq / 64; i++) { v[i] = p[lane + i * 64]; s += v[i]; }
#pragma unroll
  for (int off = 32; off; off >>= 1) s += __shfl_xor(s, off);
  float mu = s * (1.0f / Oq);
  float q = 0.f;
#pragma unroll
  for (int i = 0; i < Oq / 64; i++) { float d = v[i] - mu; q += d * d; }
#pragma unroll
  for (int off = 32; off; off >>= 1) q += __shfl_xor(q, off);
  float inv = rsqrtf(q * (1.0f / Oq) + LN_EPS);
#pragma unroll
  for (int i = 0; i < Oq / 64; i++) {
    int c = lane + i * 64;
    p[c] = (v[i] - mu) * inv * g[c] + b[c];
  }
}

extern "C" void kernel_launch(void* const* d_in, const int* in_sizes, int n_in,
                              void* d_out, int out_size, void* d_ws, size_t ws_size,
                              hipStream_t stream)
{
  const float* x    = (const float*)d_in[0];
  const float* rw   = (const float*)d_in[1];
  const float* rb   = (const float*)d_in[2];
  const float* w1   = (const float*)d_in[3];
  const float* b1   = (const float*)d_in[4];
  const float* w2   = (const float*)d_in[5];
  const float* b2   = (const float*)d_in[6];
  const float* ln_g = (const float*)d_in[7];
  const float* ln_b = (const float*)d_in[8];
  float* out = (float*)d_out;

  char* ws = (char*)d_ws;
  size_t off = 0;
  auto alloc = [&](size_t bytes) {
    void* p = ws + off;
    off += (bytes + 255) & ~(size_t)255;
    return p;
  };
  int*   cnt     = (int*)alloc(16 * 4);
  int*   prefix  = (int*)alloc(17 * 4);
  int*   seg_tok = (int*)alloc((size_t)16 * Mq * 4);
  float* seg_wgt = (float*)alloc((size_t)16 * Mq * 4);
  u16* Xbf = (u16*)alloc((size_t)Mq * Dq * 2);
  u16* W1T = (u16*)alloc((size_t)Eq * Dq * Hq * 2);
  u16* W2T = (u16*)alloc((size_t)Eq * Hq * Oq * 2);

  size_t remain = (ws_size > off) ? ws_size - off : 0;
  size_t tile_bytes = (size_t)128 * Hq * 2;   // 768 KB per slot-tile
  long long wt = (long long)(remain / tile_bytes);
  if (wt > MAX_TILES) wt = MAX_TILES;
  if (wt < 1) wt = 1;
  int WT = (int)wt;
  u16* Hbuf = (u16*)alloc((size_t)WT * tile_bytes);

  hipMemsetAsync(cnt, 0, 16 * 4, stream);
  router_cvt_kernel<<<Mq / 4, 256, 0, stream>>>(x, rw, rb, Xbf, cnt, seg_tok, seg_wgt);
  prefix_kernel<<<1, 64, 0, stream>>>(cnt, prefix);
  transpose_cvt<<<dim3(Hq / 32, Dq / 32, Eq), 256, 0, stream>>>(w1, W1T, Dq, Hq);
  transpose_cvt<<<dim3(Oq / 32, Hq / 32, Eq), 256, 0, stream>>>(w2, W2T, Hq, Oq);

  for (int tl = 0; tl < MAX_TILES; tl += WT) {
    int gx = MAX_TILES - tl; if (gx > WT) gx = WT;
    moe_gemm<0><<<dim3(gx, Hq / 128), 256, 0, stream>>>(
        Xbf, W1T, b1, Hbuf, nullptr, cnt, prefix, seg_tok, seg_wgt,
        Dq, Hq, tl, 0);
    moe_gemm<1><<<dim3(gx, Oq / 128), 256, 0, stream>>>(
        Hbuf, W2T, b2, nullptr, out, cnt, prefix, seg_tok, seg_wgt,
        Hq, Oq, tl, 0);
    moe_gemm<1><<<dim3(gx, Oq / 128), 256, 0, stream>>>(
        Hbuf, W2T, b2, nullptr, out, cnt, prefix, seg_tok, seg_wgt,
        Hq, Oq, tl, 1);
  }
  ln_kernel<<<Mq / 4, 256, 0, stream>>>(out, ln_g, ln_b);
}

// Round 4
// 949.119 us; speedup vs baseline: 2.2056x; 1.3769x over previous
//
#include <hip/hip_runtime.h>
#include <hip/hip_bf16.h>
#include <stdint.h>

#define Bq  8
#define Sq  2048
#define Dq  768
#define Hq  3072
#define Oq  768
#define Eq  8
#define Mq  (Bq*Sq)            // 16384 tokens
#define LN_EPS 1e-5f
#define MAX_TILES (2*Mq/128 + 16)   // 272 worst-case padded 128-row tiles

typedef unsigned short u16;
typedef __attribute__((ext_vector_type(4))) float f32x4;
typedef __attribute__((ext_vector_type(8))) __bf16 bf16x8;

static __device__ __forceinline__ u16 f2bf(float f) {
  __hip_bfloat16 h = __float2bfloat16(f);
  return __builtin_bit_cast(u16, h);
}

static __device__ __forceinline__ float gelu_f(float x) {
  // jax.nn.gelu approximate=True (tanh form)
  float u = 0.7978845608028654f * x * (1.0f + 0.044715f * x * x);
  float e = __expf(2.0f * u);
  float t = 1.0f - 2.0f / (e + 1.0f);   // tanh(u), NaN-free
  return 0.5f * x * (1.0f + t);
}

typedef const __attribute__((address_space(1))) void* gas_t;
typedef __attribute__((address_space(3))) void* las_t;
static __device__ __forceinline__ void gload16(const void* g, void* l) {
  __builtin_amdgcn_global_load_lds((gas_t)g, (las_t)l, 16, 0, 0);
}

// ---------------- fused router + fp32->bf16 convert. NO atomics.
// One wave per token row. Writes per-token seg pair + weight pair.
__global__ __launch_bounds__(256) void router_cvt_kernel(
    const float* __restrict__ x, const float* __restrict__ rw,
    const float* __restrict__ rb, u16* __restrict__ Xbf,
    int* __restrict__ tok_seg, float2* __restrict__ tok_w)
{
  __shared__ float rwT[Eq * Dq];      // 24 KB: rwT[e][d]
  for (int i = threadIdx.x; i < Eq * Dq; i += 256)
    rwT[(i & 7) * Dq + (i >> 3)] = rw[i];
  __syncthreads();

  int wid = threadIdx.x >> 6;
  int lane = threadIdx.x & 63;
  int token = blockIdx.x * 4 + wid;
  const float4* xrow = (const float4*)(x + (size_t)token * Dq);
  ushort4* orow = (ushort4*)(Xbf + (size_t)token * Dq);

  float acc[Eq];
#pragma unroll
  for (int e = 0; e < Eq; e++) acc[e] = 0.f;

#pragma unroll
  for (int it = 0; it < Dq / 256; it++) {
    int d4 = it * 64 + lane;                 // float4 index within row
    float4 xv = xrow[d4];
    ushort4 o;
    o.x = f2bf(xv.x); o.y = f2bf(xv.y); o.z = f2bf(xv.z); o.w = f2bf(xv.w);
    orow[d4] = o;
    int d = d4 * 4;
#pragma unroll
    for (int e = 0; e < Eq; e++) {
      float4 wv = *(const float4*)&rwT[e * Dq + d];
      acc[e] += xv.x * wv.x + xv.y * wv.y + xv.z * wv.z + xv.w * wv.w;
    }
  }
#pragma unroll
  for (int e = 0; e < Eq; e++) {
    float v = acc[e];
#pragma unroll
    for (int off = 32; off; off >>= 1) v += __shfl_xor(v, off);
    acc[e] = v;
  }
  if (lane == 0) {
    float v1 = -1e30f, v2 = -1e30f; int i1 = 0, i2 = 0;
#pragma unroll
    for (int e = 0; e < Eq; e++) {
      float v = acc[e] + rb[e];
      if (v > v1)      { v2 = v1; i2 = i1; v1 = v; i1 = e; }
      else if (v > v2) { v2 = v;  i2 = e; }
    }
    float ex = expf(v2 - v1);
    float wa = 1.f / (1.f + ex);
    float wb = ex / (1.f + ex);
    tok_seg[token] = i1 | ((8 + i2) << 8);   // rank0 seg, rank1 seg
    tok_w[token] = make_float2(wa, wb);
  }
}

// ---------------- segment-list build, block-aggregated atomics.
// 64 blocks x 256 tokens; 16 global atomics per block (64 per address).
__global__ __launch_bounds__(256) void scatter_build(
    const int* __restrict__ tok_seg, const float2* __restrict__ tok_w,
    int* __restrict__ cnt, int* __restrict__ seg_tok, float* __restrict__ seg_wgt)
{
  __shared__ int histA[16], histB[16], base[16];
  int t = threadIdx.x;
  if (t < 16) { histA[t] = 0; histB[t] = 0; }
  __syncthreads();
  int token = blockIdx.x * 256 + t;
  int sp = tok_seg[token];
  float2 wv = tok_w[token];
  int s0 = sp & 0xff, s1 = sp >> 8;
  atomicAdd(&histA[s0], 1);
  atomicAdd(&histA[s1], 1);
  __syncthreads();
  if (t < 16) base[t] = atomicAdd(&cnt[t], histA[t]);
  __syncthreads();
  int p0 = base[s0] + atomicAdd(&histB[s0], 1);
  seg_tok[(size_t)s0 * Mq + p0] = token;
  seg_wgt[(size_t)s0 * Mq + p0] = wv.x;
  int p1 = base[s1] + atomicAdd(&histB[s1], 1);
  seg_tok[(size_t)s1 * Mq + p1] = token;
  seg_wgt[(size_t)s1 * Mq + p1] = wv.y;
}

// ---------------- tile prefix over 16 segments (1 thread)
__global__ void prefix_kernel(const int* __restrict__ cnt, int* __restrict__ prefix)
{
  if (threadIdx.x == 0 && blockIdx.x == 0) {
    int t = 0;
#pragma unroll
    for (int s = 0; s < 16; s++) { prefix[s] = t; t += (cnt[s] + 127) >> 7; }
    prefix[16] = t;
  }
}

// ---------------- transpose+convert: in[R][C] f32 -> out[C][R] bf16, per expert z
__global__ __launch_bounds__(256) void transpose_cvt(
    const float* __restrict__ in, u16* __restrict__ out, int R, int C)
{
  __shared__ float tile[32][33];
  int e = blockIdx.z;
  in  += (size_t)e * R * C;
  out += (size_t)e * R * C;
  int c0 = blockIdx.x * 32, r0 = blockIdx.y * 32;
  int tx = threadIdx.x & 31, ty = threadIdx.x >> 5;   // ty 0..7
#pragma unroll
  for (int rr = 0; rr < 32; rr += 8)
    tile[rr + ty][tx] = in[(size_t)(r0 + rr + ty) * C + c0 + tx];
  __syncthreads();
#pragma unroll
  for (int rr = 0; rr < 32; rr += 8)
    out[(size_t)(c0 + rr + ty) * R + r0 + tx] = f2bf(tile[tx][rr + ty]);
}

// ---------------- grouped bf16 GEMM over padded 128-row tiles
// EPI 0 (GEMM1): A = Xbf[M][D] gathered via seg_tok; B = W1T[e][H][D];
//                Hout[localslot][Hq] = bf16(gelu(acc + b1[e][c]))
// EPI 1 (GEMM2): A = Hbuf[localslot][Hq]; B = W2T[e][O][H];
//                rank-0: out[token][c]  = (acc + b2[e][c]) * w
//                rank-1: out[token][c] += (acc + b2[e][c]) * w
template<int EPI>
__global__ __launch_bounds__(256) void moe_gemm(
    const u16* __restrict__ A, const u16* __restrict__ W,
    const float* __restrict__ bias,
    u16* __restrict__ Hout, float* __restrict__ out,
    const int* __restrict__ cnt, const int* __restrict__ prefix,
    const int* __restrict__ seg_tok, const float* __restrict__ seg_wgt,
    int K, int N, int tile_lo, int klass)
{
  const int t = tile_lo + (int)blockIdx.x;
  const int total = prefix[16];
  if (t >= total) return;
  int seg = 0;
#pragma unroll
  for (int s = 1; s < 16; s++) if (prefix[s] <= t) seg = s;
  if (EPI == 1 && (seg >> 3) != klass) return;
  const int e = seg & 7;
  const int segcnt = cnt[seg];
  const int ti = t - prefix[seg];       // tile within segment
  const int lt = t - tile_lo;           // local tile (Hbuf)

  __shared__ u16 As[128 * 32];
  __shared__ u16 Bs[128 * 32];
  const int tid  = threadIdx.x;
  const int lane = tid & 63;
  const int wid  = tid >> 6;
  const int wr   = wid >> 1, wc = wid & 1;
  const int lrow = lane & 15, kgrp = lane >> 4;
  const int n0 = blockIdx.y * 128;

  f32x4 acc[4][4];
#pragma unroll
  for (int m = 0; m < 4; m++)
#pragma unroll
    for (int n = 0; n < 4; n++) acc[m][n] = (f32x4){0.f, 0.f, 0.f, 0.f};

  // staging addresses: thread stages rows r0 and r0+64 at k-chunk (tid&3)*8
  const int r0 = tid >> 2, kc = (tid & 3) * 8;
  const u16 *gA0, *gA1;
  if (EPI == 0) {
    int i0 = ti * 128 + r0, i1 = i0 + 64;
    int tok0 = (i0 < segcnt) ? seg_tok[(size_t)seg * Mq + i0] : 0;
    int tok1 = (i1 < segcnt) ? seg_tok[(size_t)seg * Mq + i1] : 0;
    gA0 = A + (size_t)tok0 * K + kc;
    gA1 = A + (size_t)tok1 * K + kc;
  } else {
    gA0 = A + (size_t)(lt * 128 + r0) * K + kc;
    gA1 = gA0 + (size_t)64 * K;
  }
  const u16* gB = W + (size_t)e * K * N + (size_t)(n0 + r0) * K + kc;
  u16* lA = &As[tid * 8];
  u16* lB = &Bs[tid * 8];
  const size_t rowskipB = (size_t)64 * K;

  for (int k0 = 0; k0 < K; k0 += 32) {
    gload16(gA0, lA);
    gload16(gA1, lA + 2048);
    gload16(gB,            lB);
    gload16(gB + rowskipB, lB + 2048);
    gA0 += 32; gA1 += 32; gB += 32;
    __syncthreads();
    bf16x8 a[4], b[4];
#pragma unroll
    for (int m = 0; m < 4; m++)
      a[m] = *(const bf16x8*)&As[(wr * 64 + m * 16 + lrow) * 32 + kgrp * 8];
#pragma unroll
    for (int n = 0; n < 4; n++)
      b[n] = *(const bf16x8*)&Bs[(wc * 64 + n * 16 + lrow) * 32 + kgrp * 8];
#pragma unroll
    for (int m = 0; m < 4; m++)
#pragma unroll
      for (int n = 0; n < 4; n++)
        acc[m][n] = __builtin_amdgcn_mfma_f32_16x16x32_bf16(a[m], b[n], acc[m][n], 0, 0, 0);
    __syncthreads();
  }

  const int rbase = wr * 64;
  const int cbase = n0 + wc * 64;
  if (EPI == 0) {
#pragma unroll
    for (int n = 0; n < 4; n++) {
      int c = cbase + n * 16 + lrow;
      float bv = bias[(size_t)e * N + c];
#pragma unroll
      for (int m = 0; m < 4; m++)
#pragma unroll
        for (int j = 0; j < 4; j++) {
          int r = rbase + m * 16 + kgrp * 4 + j;
          float v = acc[m][n][j] + bv;
          Hout[(size_t)(lt * 128 + r) * N + c] = f2bf(gelu_f(v));
        }
    }
  } else {
#pragma unroll
    for (int m = 0; m < 4; m++)
#pragma unroll
      for (int j = 0; j < 4; j++) {
        int r = rbase + m * 16 + kgrp * 4 + j;
        int i = ti * 128 + r;
        if (i < segcnt) {
          int token = seg_tok[(size_t)seg * Mq + i];
          float w = seg_wgt[(size_t)seg * Mq + i];
          float* orow = out + (size_t)token * Oq;
#pragma unroll
          for (int n = 0; n < 4; n++) {
            int c = cbase + n * 16 + lrow;
            float v = (acc[m][n][j] + bias[(size_t)e * N + c]) * w;
            if (klass == 0) orow[c] = v;
            else            orow[c] += v;
          }
        }
      }
  }
}

// ---------------- in-place LayerNorm, one wave per row
__global__ __launch_bounds__(256) void ln_kernel(
    float* __restrict__ io, const float* __restrict__ g, const float* __restrict__ b)
{
  int wid = threadIdx.x >> 6, lane = threadIdx.x & 63;
  int row = blockIdx.x * 4 + wid;
  float* p = io + (size_t)row * Oq;
  float v[Oq / 64];
  float s = 0.f;
#pragma unroll
  for (int i = 0; i < Oq / 64; i++) { v[i] = p[lane + i * 64]; s += v[i]; }
#pragma unroll
  for (int off = 32; off; off >>= 1) s += __shfl_xor(s, off);
  float mu = s * (1.0f / Oq);
  float q = 0.f;
#pragma unroll
  for (int i = 0; i < Oq / 64; i++) { float d = v[i] - mu; q += d * d; }
#pragma unroll
  for (int off = 32; off; off >>= 1) q += __shfl_xor(q, off);
  float inv = rsqrtf(q * (1.0f / Oq) + LN_EPS);
#pragma unroll
  for (int i = 0; i < Oq / 64; i++) {
    int c = lane + i * 64;
    p[c] = (v[i] - mu) * inv * g[c] + b[c];
  }
}

extern "C" void kernel_launch(void* const* d_in, const int* in_sizes, int n_in,
                              void* d_out, int out_size, void* d_ws, size_t ws_size,
                              hipStream_t stream)
{
  const float* x    = (const float*)d_in[0];
  const float* rw   = (const float*)d_in[1];
  const float* rb   = (const float*)d_in[2];
  const float* w1   = (const float*)d_in[3];
  const float* b1   = (const float*)d_in[4];
  const float* w2   = (const float*)d_in[5];
  const float* b2   = (const float*)d_in[6];
  const float* ln_g = (const float*)d_in[7];
  const float* ln_b = (const float*)d_in[8];
  float* out = (float*)d_out;

  char* ws = (char*)d_ws;
  size_t off = 0;
  auto alloc = [&](size_t bytes) {
    void* p = ws + off;
    off += (bytes + 255) & ~(size_t)255;
    return p;
  };
  int*    cnt     = (int*)alloc(16 * 4);
  int*    prefix  = (int*)alloc(17 * 4);
  int*    tok_seg = (int*)alloc((size_t)Mq * 4);
  float2* tok_w   = (float2*)alloc((size_t)Mq * 8);
  int*    seg_tok = (int*)alloc((size_t)16 * Mq * 4);
  float*  seg_wgt = (float*)alloc((size_t)16 * Mq * 4);
  u16* Xbf = (u16*)alloc((size_t)Mq * Dq * 2);
  u16* W1T = (u16*)alloc((size_t)Eq * Dq * Hq * 2);
  u16* W2T = (u16*)alloc((size_t)Eq * Hq * Oq * 2);

  size_t remain = (ws_size > off) ? ws_size - off : 0;
  size_t tile_bytes = (size_t)128 * Hq * 2;   // 768 KB per slot-tile
  long long wt = (long long)(remain / tile_bytes);
  if (wt > MAX_TILES) wt = MAX_TILES;
  if (wt < 1) wt = 1;
  int WT = (int)wt;
  u16* Hbuf = (u16*)alloc((size_t)WT * tile_bytes);

  hipMemsetAsync(cnt, 0, 16 * 4, stream);
  router_cvt_kernel<<<Mq / 4, 256, 0, stream>>>(x, rw, rb, Xbf, tok_seg, tok_w);
  scatter_build<<<Mq / 256, 256, 0, stream>>>(tok_seg, tok_w, cnt, seg_tok, seg_wgt);
  prefix_kernel<<<1, 64, 0, stream>>>(cnt, prefix);
  transpose_cvt<<<dim3(Hq / 32, Dq / 32, Eq), 256, 0, stream>>>(w1, W1T, Dq, Hq);
  transpose_cvt<<<dim3(Oq / 32, Hq / 32, Eq), 256, 0, stream>>>(w2, W2T, Hq, Oq);

  for (int tl = 0; tl < MAX_TILES; tl += WT) {
    int gx = MAX_TILES - tl; if (gx > WT) gx = WT;
    moe_gemm<0><<<dim3(gx, Hq / 128), 256, 0, stream>>>(
        Xbf, W1T, b1, Hbuf, nullptr, cnt, prefix, seg_tok, seg_wgt,
        Dq, Hq, tl, 0);
    moe_gemm<1><<<dim3(gx, Oq / 128), 256, 0, stream>>>(
        Hbuf, W2T, b2, nullptr, out, cnt, prefix, seg_tok, seg_wgt,
        Hq, Oq, tl, 0);
    moe_gemm<1><<<dim3(gx, Oq / 128), 256, 0, stream>>>(
        Hbuf, W2T, b2, nullptr, out, cnt, prefix, seg_tok, seg_wgt,
        Hq, Oq, tl, 1);
  }
  ln_kernel<<<Mq / 4, 256, 0, stream>>>(out, ln_g, ln_b);
}

// Round 5
// 853.000 us; speedup vs baseline: 2.4542x; 1.1127x over previous
//
#include <hip/hip_runtime.h>
#include <hip/hip_bf16.h>
#include <stdint.h>

#define Bq  8
#define Sq  2048
#define Dq  768
#define Hq  3072
#define Oq  768
#define Eq  8
#define Mq  (Bq*Sq)            // 16384 tokens
#define LN_EPS 1e-5f
#define MAX_TILES (2*Mq/128 + 16)   // 272 worst-case padded 128-row tiles

typedef unsigned short u16;
typedef __attribute__((ext_vector_type(4))) float f32x4;
typedef __attribute__((ext_vector_type(8))) __bf16 bf16x8;

static __device__ __forceinline__ u16 f2bf(float f) {
  __hip_bfloat16 h = __float2bfloat16(f);
  return __builtin_bit_cast(u16, h);
}

static __device__ __forceinline__ float gelu_f(float x) {
  // jax.nn.gelu approximate=True (tanh form)
  float u = 0.7978845608028654f * x * (1.0f + 0.044715f * x * x);
  float e = __expf(2.0f * u);
  float t = 1.0f - 2.0f / (e + 1.0f);   // tanh(u), NaN-free
  return 0.5f * x * (1.0f + t);
}

typedef const __attribute__((address_space(1))) void* gas_t;
typedef __attribute__((address_space(3))) void* las_t;
static __device__ __forceinline__ void gload16(const void* g, void* l) {
  __builtin_amdgcn_global_load_lds((gas_t)g, (las_t)l, 16, 0, 0);
}

// ---------------- fused router + fp32->bf16 convert. NO atomics.
// One wave per token row. Writes per-token seg pair + weight pair.
__global__ __launch_bounds__(256) void router_cvt_kernel(
    const float* __restrict__ x, const float* __restrict__ rw,
    const float* __restrict__ rb, u16* __restrict__ Xbf,
    int* __restrict__ tok_seg, float2* __restrict__ tok_w)
{
  __shared__ float rwT[Eq * Dq];      // 24 KB: rwT[e][d]
  for (int i = threadIdx.x; i < Eq * Dq; i += 256)
    rwT[(i & 7) * Dq + (i >> 3)] = rw[i];
  __syncthreads();

  int wid = threadIdx.x >> 6;
  int lane = threadIdx.x & 63;
  int token = blockIdx.x * 4 + wid;
  const float4* xrow = (const float4*)(x + (size_t)token * Dq);
  ushort4* orow = (ushort4*)(Xbf + (size_t)token * Dq);

  float acc[Eq];
#pragma unroll
  for (int e = 0; e < Eq; e++) acc[e] = 0.f;

#pragma unroll
  for (int it = 0; it < Dq / 256; it++) {
    int d4 = it * 64 + lane;                 // float4 index within row
    float4 xv = xrow[d4];
    ushort4 o;
    o.x = f2bf(xv.x); o.y = f2bf(xv.y); o.z = f2bf(xv.z); o.w = f2bf(xv.w);
    orow[d4] = o;
    int d = d4 * 4;
#pragma unroll
    for (int e = 0; e < Eq; e++) {
      float4 wv = *(const float4*)&rwT[e * Dq + d];
      acc[e] += xv.x * wv.x + xv.y * wv.y + xv.z * wv.z + xv.w * wv.w;
    }
  }
#pragma unroll
  for (int e = 0; e < Eq; e++) {
    float v = acc[e];
#pragma unroll
    for (int off = 32; off; off >>= 1) v += __shfl_xor(v, off);
    acc[e] = v;
  }
  if (lane == 0) {
    float v1 = -1e30f, v2 = -1e30f; int i1 = 0, i2 = 0;
#pragma unroll
    for (int e = 0; e < Eq; e++) {
      float v = acc[e] + rb[e];
      if (v > v1)      { v2 = v1; i2 = i1; v1 = v; i1 = e; }
      else if (v > v2) { v2 = v;  i2 = e; }
    }
    float ex = expf(v2 - v1);
    float wa = 1.f / (1.f + ex);
    float wb = ex / (1.f + ex);
    tok_seg[token] = i1 | ((8 + i2) << 8);   // rank0 seg, rank1 seg
    tok_w[token] = make_float2(wa, wb);
  }
}

// ---------------- segment-list build, block-aggregated atomics.
// 64 blocks x 256 tokens; 16 global atomics per block (64 per address).
__global__ __launch_bounds__(256) void scatter_build(
    const int* __restrict__ tok_seg, const float2* __restrict__ tok_w,
    int* __restrict__ cnt, int* __restrict__ seg_tok, float* __restrict__ seg_wgt)
{
  __shared__ int histA[16], histB[16], base[16];
  int t = threadIdx.x;
  if (t < 16) { histA[t] = 0; histB[t] = 0; }
  __syncthreads();
  int token = blockIdx.x * 256 + t;
  int sp = tok_seg[token];
  float2 wv = tok_w[token];
  int s0 = sp & 0xff, s1 = sp >> 8;
  atomicAdd(&histA[s0], 1);
  atomicAdd(&histA[s1], 1);
  __syncthreads();
  if (t < 16) base[t] = atomicAdd(&cnt[t], histA[t]);
  __syncthreads();
  int p0 = base[s0] + atomicAdd(&histB[s0], 1);
  seg_tok[(size_t)s0 * Mq + p0] = token;
  seg_wgt[(size_t)s0 * Mq + p0] = wv.x;
  int p1 = base[s1] + atomicAdd(&histB[s1], 1);
  seg_tok[(size_t)s1 * Mq + p1] = token;
  seg_wgt[(size_t)s1 * Mq + p1] = wv.y;
}

// ---------------- tile prefix over 16 segments (1 thread)
__global__ void prefix_kernel(const int* __restrict__ cnt, int* __restrict__ prefix)
{
  if (threadIdx.x == 0 && blockIdx.x == 0) {
    int t = 0;
#pragma unroll
    for (int s = 0; s < 16; s++) { prefix[s] = t; t += (cnt[s] + 127) >> 7; }
    prefix[16] = t;
  }
}

// ---------------- transpose+convert: in[R][C] f32 -> out[C][R] bf16, per expert z
__global__ __launch_bounds__(256) void transpose_cvt(
    const float* __restrict__ in, u16* __restrict__ out, int R, int C)
{
  __shared__ float tile[32][33];
  int e = blockIdx.z;
  in  += (size_t)e * R * C;
  out += (size_t)e * R * C;
  int c0 = blockIdx.x * 32, r0 = blockIdx.y * 32;
  int tx = threadIdx.x & 31, ty = threadIdx.x >> 5;   // ty 0..7
#pragma unroll
  for (int rr = 0; rr < 32; rr += 8)
    tile[rr + ty][tx] = in[(size_t)(r0 + rr + ty) * C + c0 + tx];
  __syncthreads();
#pragma unroll
  for (int rr = 0; rr < 32; rr += 8)
    out[(size_t)(c0 + rr + ty) * R + r0 + tx] = f2bf(tile[tx][rr + ty]);
}

// ---------------- grouped bf16 GEMM over padded 128-row tiles
// GRID: blockIdx.x = n-panel (FAST — panels sharing an A row-tile launch
// back-to-back so the tile is L3-resident for all of them), blockIdx.y = tile.
// EPI 0 (GEMM1): A = Xbf[M][D] gathered via seg_tok; B = W1T[e][H][D];
//                Hout[localslot][Hq] = bf16(gelu(acc + b1[e][c]))
// EPI 1 (GEMM2): A = Hbuf[localslot][Hq]; B = W2T[e][O][H];
//                rank-0: out[token][c]  = (acc + b2[e][c]) * w
//                rank-1: out[token][c] += (acc + b2[e][c]) * w
template<int EPI>
__global__ __launch_bounds__(256) void moe_gemm(
    const u16* __restrict__ A, const u16* __restrict__ W,
    const float* __restrict__ bias,
    u16* __restrict__ Hout, float* __restrict__ out,
    const int* __restrict__ cnt, const int* __restrict__ prefix,
    const int* __restrict__ seg_tok, const float* __restrict__ seg_wgt,
    int K, int N, int tile_lo, int klass)
{
  const int t = tile_lo + (int)blockIdx.y;
  const int total = prefix[16];
  if (t >= total) return;
  int seg = 0;
#pragma unroll
  for (int s = 1; s < 16; s++) if (prefix[s] <= t) seg = s;
  if (EPI == 1 && (seg >> 3) != klass) return;
  const int e = seg & 7;
  const int segcnt = cnt[seg];
  const int ti = t - prefix[seg];       // tile within segment
  const int lt = t - tile_lo;           // local tile (Hbuf)

  __shared__ u16 As[128 * 32];
  __shared__ u16 Bs[128 * 32];
  const int tid  = threadIdx.x;
  const int lane = tid & 63;
  const int wid  = tid >> 6;
  const int wr   = wid >> 1, wc = wid & 1;
  const int lrow = lane & 15, kgrp = lane >> 4;
  const int n0 = blockIdx.x * 128;

  f32x4 acc[4][4];
#pragma unroll
  for (int m = 0; m < 4; m++)
#pragma unroll
    for (int n = 0; n < 4; n++) acc[m][n] = (f32x4){0.f, 0.f, 0.f, 0.f};

  // staging addresses: thread stages rows r0 and r0+64 at k-chunk (tid&3)*8
  const int r0 = tid >> 2, kc = (tid & 3) * 8;
  const u16 *gA0, *gA1;
  if (EPI == 0) {
    int i0 = ti * 128 + r0, i1 = i0 + 64;
    int tok0 = (i0 < segcnt) ? seg_tok[(size_t)seg * Mq + i0] : 0;
    int tok1 = (i1 < segcnt) ? seg_tok[(size_t)seg * Mq + i1] : 0;
    gA0 = A + (size_t)tok0 * K + kc;
    gA1 = A + (size_t)tok1 * K + kc;
  } else {
    gA0 = A + (size_t)(lt * 128 + r0) * K + kc;
    gA1 = gA0 + (size_t)64 * K;
  }
  const u16* gB = W + (size_t)e * K * N + (size_t)(n0 + r0) * K + kc;
  u16* lA = &As[tid * 8];
  u16* lB = &Bs[tid * 8];
  const size_t rowskipB = (size_t)64 * K;

  for (int k0 = 0; k0 < K; k0 += 32) {
    gload16(gA0, lA);
    gload16(gA1, lA + 2048);
    gload16(gB,            lB);
    gload16(gB + rowskipB, lB + 2048);
    gA0 += 32; gA1 += 32; gB += 32;
    __syncthreads();
    bf16x8 a[4], b[4];
#pragma unroll
    for (int m = 0; m < 4; m++)
      a[m] = *(const bf16x8*)&As[(wr * 64 + m * 16 + lrow) * 32 + kgrp * 8];
#pragma unroll
    for (int n = 0; n < 4; n++)
      b[n] = *(const bf16x8*)&Bs[(wc * 64 + n * 16 + lrow) * 32 + kgrp * 8];
#pragma unroll
    for (int m = 0; m < 4; m++)
#pragma unroll
      for (int n = 0; n < 4; n++)
        acc[m][n] = __builtin_amdgcn_mfma_f32_16x16x32_bf16(a[m], b[n], acc[m][n], 0, 0, 0);
    __syncthreads();
  }

  const int rbase = wr * 64;
  const int cbase = n0 + wc * 64;
  if (EPI == 0) {
#pragma unroll
    for (int n = 0; n < 4; n++) {
      int c = cbase + n * 16 + lrow;
      float bv = bias[(size_t)e * N + c];
#pragma unroll
      for (int m = 0; m < 4; m++)
#pragma unroll
        for (int j = 0; j < 4; j++) {
          int r = rbase + m * 16 + kgrp * 4 + j;
          float v = acc[m][n][j] + bv;
          Hout[(size_t)(lt * 128 + r) * N + c] = f2bf(gelu_f(v));
        }
    }
  } else {
#pragma unroll
    for (int m = 0; m < 4; m++)
#pragma unroll
      for (int j = 0; j < 4; j++) {
        int r = rbase + m * 16 + kgrp * 4 + j;
        int i = ti * 128 + r;
        if (i < segcnt) {
          int token = seg_tok[(size_t)seg * Mq + i];
          float w = seg_wgt[(size_t)seg * Mq + i];
          float* orow = out + (size_t)token * Oq;
#pragma unroll
          for (int n = 0; n < 4; n++) {
            int c = cbase + n * 16 + lrow;
            float v = (acc[m][n][j] + bias[(size_t)e * N + c]) * w;
            if (klass == 0) orow[c] = v;
            else            orow[c] += v;
          }
        }
      }
  }
}

// ---------------- in-place LayerNorm, one wave per row
__global__ __launch_bounds__(256) void ln_kernel(
    float* __restrict__ io, const float* __restrict__ g, const float* __restrict__ b)
{
  int wid = threadIdx.x >> 6, lane = threadIdx.x & 63;
  int row = blockIdx.x * 4 + wid;
  float* p = io + (size_t)row * Oq;
  float v[Oq / 64];
  float s = 0.f;
#pragma unroll
  for (int i = 0; i < Oq / 64; i++) { v[i] = p[lane + i * 64]; s += v[i]; }
#pragma unroll
  for (int off = 32; off; off >>= 1) s += __shfl_xor(s, off);
  float mu = s * (1.0f / Oq);
  float q = 0.f;
#pragma unroll
  for (int i = 0; i < Oq / 64; i++) { float d = v[i] - mu; q += d * d; }
#pragma unroll
  for (int off = 32; off; off >>= 1) q += __shfl_xor(q, off);
  float inv = rsqrtf(q * (1.0f / Oq) + LN_EPS);
#pragma unroll
  for (int i = 0; i < Oq / 64; i++) {
    int c = lane + i * 64;
    p[c] = (v[i] - mu) * inv * g[c] + b[c];
  }
}

extern "C" void kernel_launch(void* const* d_in, const int* in_sizes, int n_in,
                              void* d_out, int out_size, void* d_ws, size_t ws_size,
                              hipStream_t stream)
{
  const float* x    = (const float*)d_in[0];
  const float* rw   = (const float*)d_in[1];
  const float* rb   = (const float*)d_in[2];
  const float* w1   = (const float*)d_in[3];
  const float* b1   = (const float*)d_in[4];
  const float* w2   = (const float*)d_in[5];
  const float* b2   = (const float*)d_in[6];
  const float* ln_g = (const float*)d_in[7];
  const float* ln_b = (const float*)d_in[8];
  float* out = (float*)d_out;

  char* ws = (char*)d_ws;
  size_t off = 0;
  auto alloc = [&](size_t bytes) {
    void* p = ws + off;
    off += (bytes + 255) & ~(size_t)255;
    return p;
  };
  int*    cnt     = (int*)alloc(16 * 4);
  int*    prefix  = (int*)alloc(17 * 4);
  int*    tok_seg = (int*)alloc((size_t)Mq * 4);
  float2* tok_w   = (float2*)alloc((size_t)Mq * 8);
  int*    seg_tok = (int*)alloc((size_t)16 * Mq * 4);
  float*  seg_wgt = (float*)alloc((size_t)16 * Mq * 4);
  u16* Xbf = (u16*)alloc((size_t)Mq * Dq * 2);
  u16* W1T = (u16*)alloc((size_t)Eq * Dq * Hq * 2);
  u16* W2T = (u16*)alloc((size_t)Eq * Hq * Oq * 2);

  size_t remain = (ws_size > off) ? ws_size - off : 0;
  size_t tile_bytes = (size_t)128 * Hq * 2;   // 768 KB per slot-tile
  long long wt = (long long)(remain / tile_bytes);
  if (wt > MAX_TILES) wt = MAX_TILES;
  if (wt < 1) wt = 1;
  int WT = (int)wt;
  u16* Hbuf = (u16*)alloc((size_t)WT * tile_bytes);

  hipMemsetAsync(cnt, 0, 16 * 4, stream);
  router_cvt_kernel<<<Mq / 4, 256, 0, stream>>>(x, rw, rb, Xbf, tok_seg, tok_w);
  scatter_build<<<Mq / 256, 256, 0, stream>>>(tok_seg, tok_w, cnt, seg_tok, seg_wgt);
  prefix_kernel<<<1, 64, 0, stream>>>(cnt, prefix);
  transpose_cvt<<<dim3(Hq / 32, Dq / 32, Eq), 256, 0, stream>>>(w1, W1T, Dq, Hq);
  transpose_cvt<<<dim3(Oq / 32, Hq / 32, Eq), 256, 0, stream>>>(w2, W2T, Hq, Oq);

  for (int tl = 0; tl < MAX_TILES; tl += WT) {
    int gx = MAX_TILES - tl; if (gx > WT) gx = WT;
    moe_gemm<0><<<dim3(Hq / 128, gx), 256, 0, stream>>>(
        Xbf, W1T, b1, Hbuf, nullptr, cnt, prefix, seg_tok, seg_wgt,
        Dq, Hq, tl, 0);
    moe_gemm<1><<<dim3(Oq / 128, gx), 256, 0, stream>>>(
        Hbuf, W2T, b2, nullptr, out, cnt, prefix, seg_tok, seg_wgt,
        Hq, Oq, tl, 0);
    moe_gemm<1><<<dim3(Oq / 128, gx), 256, 0, stream>>>(
        Hbuf, W2T, b2, nullptr, out, cnt, prefix, seg_tok, seg_wgt,
        Hq, Oq, tl, 1);
  }
  ln_kernel<<<Mq / 4, 256, 0, stream>>>(out, ln_g, ln_b);
}

// Round 6
// 808.332 us; speedup vs baseline: 2.5898x; 1.0553x over previous
//
#include <hip/hip_runtime.h>
#include <hip/hip_bf16.h>
#include <stdint.h>

#define Bq  8
#define Sq  2048
#define Dq  768
#define Hq  3072
#define Oq  768
#define Eq  8
#define Mq  (Bq*Sq)            // 16384 tokens
#define LN_EPS 1e-5f
#define MAX_TILES (2*Mq/128 + 16)   // 272 worst-case padded 128-row tiles

typedef unsigned short u16;
typedef __attribute__((ext_vector_type(4))) float f32x4;
typedef __attribute__((ext_vector_type(8))) __bf16 bf16x8;

static __device__ __forceinline__ u16 f2bf(float f) {
  __hip_bfloat16 h = __float2bfloat16(f);
  return __builtin_bit_cast(u16, h);
}

static __device__ __forceinline__ float gelu_f(float x) {
  // jax.nn.gelu approximate=True (tanh form)
  float u = 0.7978845608028654f * x * (1.0f + 0.044715f * x * x);
  float e = __expf(2.0f * u);
  float t = 1.0f - 2.0f / (e + 1.0f);   // tanh(u), NaN-free
  return 0.5f * x * (1.0f + t);
}

typedef const __attribute__((address_space(1))) void* gas_t;
typedef __attribute__((address_space(3))) void* las_t;
static __device__ __forceinline__ void gload16(const void* g, void* l) {
  __builtin_amdgcn_global_load_lds((gas_t)g, (las_t)l, 16, 0, 0);
}

// ---------------- fused router + fp32->bf16 convert. NO atomics.
// One wave per token row. Writes per-token seg pair + weight pair.
__global__ __launch_bounds__(256) void router_cvt_kernel(
    const float* __restrict__ x, const float* __restrict__ rw,
    const float* __restrict__ rb, u16* __restrict__ Xbf,
    int* __restrict__ tok_seg, float2* __restrict__ tok_w)
{
  __shared__ float rwT[Eq * Dq];      // 24 KB: rwT[e][d]
  for (int i = threadIdx.x; i < Eq * Dq; i += 256)
    rwT[(i & 7) * Dq + (i >> 3)] = rw[i];
  __syncthreads();

  int wid = threadIdx.x >> 6;
  int lane = threadIdx.x & 63;
  int token = blockIdx.x * 4 + wid;
  const float4* xrow = (const float4*)(x + (size_t)token * Dq);
  ushort4* orow = (ushort4*)(Xbf + (size_t)token * Dq);

  float acc[Eq];
#pragma unroll
  for (int e = 0; e < Eq; e++) acc[e] = 0.f;

#pragma unroll
  for (int it = 0; it < Dq / 256; it++) {
    int d4 = it * 64 + lane;                 // float4 index within row
    float4 xv = xrow[d4];
    ushort4 o;
    o.x = f2bf(xv.x); o.y = f2bf(xv.y); o.z = f2bf(xv.z); o.w = f2bf(xv.w);
    orow[d4] = o;
    int d = d4 * 4;
#pragma unroll
    for (int e = 0; e < Eq; e++) {
      float4 wv = *(const float4*)&rwT[e * Dq + d];
      acc[e] += xv.x * wv.x + xv.y * wv.y + xv.z * wv.z + xv.w * wv.w;
    }
  }
#pragma unroll
  for (int e = 0; e < Eq; e++) {
    float v = acc[e];
#pragma unroll
    for (int off = 32; off; off >>= 1) v += __shfl_xor(v, off);
    acc[e] = v;
  }
  if (lane == 0) {
    float v1 = -1e30f, v2 = -1e30f; int i1 = 0, i2 = 0;
#pragma unroll
    for (int e = 0; e < Eq; e++) {
      float v = acc[e] + rb[e];
      if (v > v1)      { v2 = v1; i2 = i1; v1 = v; i1 = e; }
      else if (v > v2) { v2 = v;  i2 = e; }
    }
    float ex = expf(v2 - v1);
    float wa = 1.f / (1.f + ex);
    float wb = ex / (1.f + ex);
    tok_seg[token] = i1 | ((8 + i2) << 8);   // rank0 seg, rank1 seg
    tok_w[token] = make_float2(wa, wb);
  }
}

// ---------------- segment-list build, block-aggregated atomics.
// 64 blocks x 256 tokens; 16 global atomics per block (64 per address).
__global__ __launch_bounds__(256) void scatter_build(
    const int* __restrict__ tok_seg, const float2* __restrict__ tok_w,
    int* __restrict__ cnt, int* __restrict__ seg_tok, float* __restrict__ seg_wgt)
{
  __shared__ int histA[16], histB[16], base[16];
  int t = threadIdx.x;
  if (t < 16) { histA[t] = 0; histB[t] = 0; }
  __syncthreads();
  int token = blockIdx.x * 256 + t;
  int sp = tok_seg[token];
  float2 wv = tok_w[token];
  int s0 = sp & 0xff, s1 = sp >> 8;
  atomicAdd(&histA[s0], 1);
  atomicAdd(&histA[s1], 1);
  __syncthreads();
  if (t < 16) base[t] = atomicAdd(&cnt[t], histA[t]);
  __syncthreads();
  int p0 = base[s0] + atomicAdd(&histB[s0], 1);
  seg_tok[(size_t)s0 * Mq + p0] = token;
  seg_wgt[(size_t)s0 * Mq + p0] = wv.x;
  int p1 = base[s1] + atomicAdd(&histB[s1], 1);
  seg_tok[(size_t)s1 * Mq + p1] = token;
  seg_wgt[(size_t)s1 * Mq + p1] = wv.y;
}

// ---------------- tile prefix over 16 segments (1 thread)
__global__ void prefix_kernel(const int* __restrict__ cnt, int* __restrict__ prefix)
{
  if (threadIdx.x == 0 && blockIdx.x == 0) {
    int t = 0;
#pragma unroll
    for (int s = 0; s < 16; s++) { prefix[s] = t; t += (cnt[s] + 127) >> 7; }
    prefix[16] = t;
  }
}

// ---------------- transpose+convert: in[R][C] f32 -> out[C][R] bf16, per expert z
__global__ __launch_bounds__(256) void transpose_cvt(
    const float* __restrict__ in, u16* __restrict__ out, int R, int C)
{
  __shared__ float tile[32][33];
  int e = blockIdx.z;
  in  += (size_t)e * R * C;
  out += (size_t)e * R * C;
  int c0 = blockIdx.x * 32, r0 = blockIdx.y * 32;
  int tx = threadIdx.x & 31, ty = threadIdx.x >> 5;   // ty 0..7
#pragma unroll
  for (int rr = 0; rr < 32; rr += 8)
    tile[rr + ty][tx] = in[(size_t)(r0 + rr + ty) * C + c0 + tx];
  __syncthreads();
#pragma unroll
  for (int rr = 0; rr < 32; rr += 8)
    out[(size_t)(c0 + rr + ty) * R + r0 + tx] = f2bf(tile[tx][rr + ty]);
}

// ---------------- grouped bf16 GEMM over padded 128-row tiles
// GRID: blockIdx.x = n-panel (FAST), blockIdx.y = tile.
// LDS staging is bank-conflict-swizzled BOTH-sides (rule 21): global source
// chunk index is XOR'd with (row>>1)&3, LDS dst stays linear (gload_lds),
// fragment ds_read applies the matching XOR.
// EPI 0 (GEMM1): A = Xbf[M][D] gathered via seg_tok; B = W1T[e][H][D];
//                Hout[localslot][Hq] = bf16(gelu(acc + b1[e][c]))
// EPI 1 (GEMM2): A = Hbuf[localslot][Hq]; B = W2T[e][O][H];
//                out[token][c] += (acc + b2[e][c]) * w   (HW f32 atomic,
//                out pre-zeroed; 2 commutative adds/element -> deterministic)
template<int EPI>
__global__ __launch_bounds__(256) void moe_gemm(
    const u16* __restrict__ A, const u16* __restrict__ W,
    const float* __restrict__ bias,
    u16* __restrict__ Hout, float* __restrict__ out,
    const int* __restrict__ cnt, const int* __restrict__ prefix,
    const int* __restrict__ seg_tok, const float* __restrict__ seg_wgt,
    int K, int N, int tile_lo)
{
  const int t = tile_lo + (int)blockIdx.y;
  const int total = prefix[16];
  if (t >= total) return;
  int seg = 0;
#pragma unroll
  for (int s = 1; s < 16; s++) if (prefix[s] <= t) seg = s;
  const int e = seg & 7;
  const int segcnt = cnt[seg];
  const int ti = t - prefix[seg];       // tile within segment
  const int lt = t - tile_lo;           // local tile (Hbuf)

  __shared__ u16 As[128 * 32];
  __shared__ u16 Bs[128 * 32];
  const int tid  = threadIdx.x;
  const int lane = tid & 63;
  const int wid  = tid >> 6;
  const int wr   = wid >> 1, wc = wid & 1;
  const int lrow = lane & 15, kgrp = lane >> 4;
  const int kx   = kgrp ^ ((lrow >> 1) & 3);   // swizzled read chunk
  const int n0 = blockIdx.x * 128;

  f32x4 acc[4][4];
#pragma unroll
  for (int m = 0; m < 4; m++)
#pragma unroll
    for (int n = 0; n < 4; n++) acc[m][n] = (f32x4){0.f, 0.f, 0.f, 0.f};

  // staging: thread stages rows r0 and r0+64; source k-chunk is swizzled by row
  const int r0 = tid >> 2;
  const int kc = (((tid & 3) ^ ((tid >> 3) & 3)) * 8);
  const u16 *gA0, *gA1;
  if (EPI == 0) {
    int i0 = ti * 128 + r0, i1 = i0 + 64;
    int tok0 = (i0 < segcnt) ? seg_tok[(size_t)seg * Mq + i0] : 0;
    int tok1 = (i1 < segcnt) ? seg_tok[(size_t)seg * Mq + i1] : 0;
    gA0 = A + (size_t)tok0 * K + kc;
    gA1 = A + (size_t)tok1 * K + kc;
  } else {
    gA0 = A + (size_t)(lt * 128 + r0) * K + kc;
    gA1 = gA0 + (size_t)64 * K;
  }
  const u16* gB = W + (size_t)e * K * N + (size_t)(n0 + r0) * K + kc;
  u16* lA = &As[tid * 8];
  u16* lB = &Bs[tid * 8];
  const size_t rowskipB = (size_t)64 * K;

  for (int k0 = 0; k0 < K; k0 += 32) {
    gload16(gA0, lA);
    gload16(gA1, lA + 2048);
    gload16(gB,            lB);
    gload16(gB + rowskipB, lB + 2048);
    gA0 += 32; gA1 += 32; gB += 32;
    __syncthreads();
    bf16x8 a[4], b[4];
#pragma unroll
    for (int m = 0; m < 4; m++)
      a[m] = *(const bf16x8*)&As[(wr * 64 + m * 16 + lrow) * 32 + kx * 8];
#pragma unroll
    for (int n = 0; n < 4; n++)
      b[n] = *(const bf16x8*)&Bs[(wc * 64 + n * 16 + lrow) * 32 + kx * 8];
#pragma unroll
    for (int m = 0; m < 4; m++)
#pragma unroll
      for (int n = 0; n < 4; n++)
        acc[m][n] = __builtin_amdgcn_mfma_f32_16x16x32_bf16(a[m], b[n], acc[m][n], 0, 0, 0);
    __syncthreads();
  }

  const int rbase = wr * 64;
  const int cbase = n0 + wc * 64;
  if (EPI == 0) {
#pragma unroll
    for (int n = 0; n < 4; n++) {
      int c = cbase + n * 16 + lrow;
      float bv = bias[(size_t)e * N + c];
#pragma unroll
      for (int m = 0; m < 4; m++)
#pragma unroll
        for (int j = 0; j < 4; j++) {
          int r = rbase + m * 16 + kgrp * 4 + j;
          float v = acc[m][n][j] + bv;
          Hout[(size_t)(lt * 128 + r) * N + c] = f2bf(gelu_f(v));
        }
    }
  } else {
#pragma unroll
    for (int m = 0; m < 4; m++)
#pragma unroll
      for (int j = 0; j < 4; j++) {
        int r = rbase + m * 16 + kgrp * 4 + j;
        int i = ti * 128 + r;
        if (i < segcnt) {
          int token = seg_tok[(size_t)seg * Mq + i];
          float w = seg_wgt[(size_t)seg * Mq + i];
          float* orow = out + (size_t)token * Oq;
#pragma unroll
          for (int n = 0; n < 4; n++) {
            int c = cbase + n * 16 + lrow;
            float v = (acc[m][n][j] + bias[(size_t)e * N + c]) * w;
            unsafeAtomicAdd(&orow[c], v);
          }
        }
      }
  }
}

// ---------------- in-place LayerNorm, one wave per row
__global__ __launch_bounds__(256) void ln_kernel(
    float* __restrict__ io, const float* __restrict__ g, const float* __restrict__ b)
{
  int wid = threadIdx.x >> 6, lane = threadIdx.x & 63;
  int row = blockIdx.x * 4 + wid;
  float* p = io + (size_t)row * Oq;
  float v[Oq / 64];
  float s = 0.f;
#pragma unroll
  for (int i = 0; i < Oq / 64; i++) { v[i] = p[lane + i * 64]; s += v[i]; }
#pragma unroll
  for (int off = 32; off; off >>= 1) s += __shfl_xor(s, off);
  float mu = s * (1.0f / Oq);
  float q = 0.f;
#pragma unroll
  for (int i = 0; i < Oq / 64; i++) { float d = v[i] - mu; q += d * d; }
#pragma unroll
  for (int off = 32; off; off >>= 1) q += __shfl_xor(q, off);
  float inv = rsqrtf(q * (1.0f / Oq) + LN_EPS);
#pragma unroll
  for (int i = 0; i < Oq / 64; i++) {
    int c = lane + i * 64;
    p[c] = (v[i] - mu) * inv * g[c] + b[c];
  }
}

extern "C" void kernel_launch(void* const* d_in, const int* in_sizes, int n_in,
                              void* d_out, int out_size, void* d_ws, size_t ws_size,
                              hipStream_t stream)
{
  const float* x    = (const float*)d_in[0];
  const float* rw   = (const float*)d_in[1];
  const float* rb   = (const float*)d_in[2];
  const float* w1   = (const float*)d_in[3];
  const float* b1   = (const float*)d_in[4];
  const float* w2   = (const float*)d_in[5];
  const float* b2   = (const float*)d_in[6];
  const float* ln_g = (const float*)d_in[7];
  const float* ln_b = (const float*)d_in[8];
  float* out = (float*)d_out;

  char* ws = (char*)d_ws;
  size_t off = 0;
  auto alloc = [&](size_t bytes) {
    void* p = ws + off;
    off += (bytes + 255) & ~(size_t)255;
    return p;
  };
  int*    cnt     = (int*)alloc(16 * 4);
  int*    prefix  = (int*)alloc(17 * 4);
  int*    tok_seg = (int*)alloc((size_t)Mq * 4);
  float2* tok_w   = (float2*)alloc((size_t)Mq * 8);
  int*    seg_tok = (int*)alloc((size_t)16 * Mq * 4);
  float*  seg_wgt = (float*)alloc((size_t)16 * Mq * 4);
  u16* Xbf = (u16*)alloc((size_t)Mq * Dq * 2);
  u16* W1T = (u16*)alloc((size_t)Eq * Dq * Hq * 2);
  u16* W2T = (u16*)alloc((size_t)Eq * Hq * Oq * 2);

  size_t remain = (ws_size > off) ? ws_size - off : 0;
  size_t tile_bytes = (size_t)128 * Hq * 2;   // 768 KB per slot-tile
  long long wt = (long long)(remain / tile_bytes);
  if (wt > MAX_TILES) wt = MAX_TILES;
  if (wt < 1) wt = 1;
  int WT = (int)wt;
  u16* Hbuf = (u16*)alloc((size_t)WT * tile_bytes);

  hipMemsetAsync(out, 0, (size_t)Mq * Oq * 4, stream);
  hipMemsetAsync(cnt, 0, 16 * 4, stream);
  router_cvt_kernel<<<Mq / 4, 256, 0, stream>>>(x, rw, rb, Xbf, tok_seg, tok_w);
  scatter_build<<<Mq / 256, 256, 0, stream>>>(tok_seg, tok_w, cnt, seg_tok, seg_wgt);
  prefix_kernel<<<1, 64, 0, stream>>>(cnt, prefix);
  transpose_cvt<<<dim3(Hq / 32, Dq / 32, Eq), 256, 0, stream>>>(w1, W1T, Dq, Hq);
  transpose_cvt<<<dim3(Oq / 32, Hq / 32, Eq), 256, 0, stream>>>(w2, W2T, Hq, Oq);

  for (int tl = 0; tl < MAX_TILES; tl += WT) {
    int gx = MAX_TILES - tl; if (gx > WT) gx = WT;
    moe_gemm<0><<<dim3(Hq / 128, gx), 256, 0, stream>>>(
        Xbf, W1T, b1, Hbuf, nullptr, cnt, prefix, seg_tok, seg_wgt,
        Dq, Hq, tl);
    moe_gemm<1><<<dim3(Oq / 128, gx), 256, 0, stream>>>(
        Hbuf, W2T, b2, nullptr, out, cnt, prefix, seg_tok, seg_wgt,
        Hq, Oq, tl);
  }
  ln_kernel<<<Mq / 4, 256, 0, stream>>>(out, ln_g, ln_b);
}

// Round 7
// 798.130 us; speedup vs baseline: 2.6229x; 1.0128x over previous
//
#include <hip/hip_runtime.h>
#include <hip/hip_bf16.h>
#include <stdint.h>

#define Bq  8
#define Sq  2048
#define Dq  768
#define Hq  3072
#define Oq  768
#define Eq  8
#define Mq  (Bq*Sq)            // 16384 tokens
#define LN_EPS 1e-5f
#define MAX_TILES (2*Mq/128 + 16)   // 272 worst-case padded 128-row tiles
#define WT_CAP 96                   // L3-residency: 96*768KB = 72 MB Hbuf chunk

typedef unsigned short u16;
typedef __attribute__((ext_vector_type(4))) float f32x4;
typedef __attribute__((ext_vector_type(8))) __bf16 bf16x8;

static __device__ __forceinline__ u16 f2bf(float f) {
  __hip_bfloat16 h = __float2bfloat16(f);
  return __builtin_bit_cast(u16, h);
}

static __device__ __forceinline__ float gelu_f(float x) {
  // jax.nn.gelu approximate=True (tanh form)
  float u = 0.7978845608028654f * x * (1.0f + 0.044715f * x * x);
  float e = __expf(2.0f * u);
  float t = 1.0f - 2.0f / (e + 1.0f);   // tanh(u), NaN-free
  return 0.5f * x * (1.0f + t);
}

typedef const __attribute__((address_space(1))) void* gas_t;
typedef __attribute__((address_space(3))) void* las_t;
static __device__ __forceinline__ void gload16(const void* g, void* l) {
  __builtin_amdgcn_global_load_lds((gas_t)g, (las_t)l, 16, 0, 0);
}

// ---------------- fused router + fp32->bf16 convert. NO atomics.
// One wave per token row. Writes per-token seg pair + weight pair.
__global__ __launch_bounds__(256) void router_cvt_kernel(
    const float* __restrict__ x, const float* __restrict__ rw,
    const float* __restrict__ rb, u16* __restrict__ Xbf,
    int* __restrict__ tok_seg, float2* __restrict__ tok_w)
{
  __shared__ float rwT[Eq * Dq];      // 24 KB: rwT[e][d]
  for (int i = threadIdx.x; i < Eq * Dq; i += 256)
    rwT[(i & 7) * Dq + (i >> 3)] = rw[i];
  __syncthreads();

  int wid = threadIdx.x >> 6;
  int lane = threadIdx.x & 63;
  int token = blockIdx.x * 4 + wid;
  const float4* xrow = (const float4*)(x + (size_t)token * Dq);
  ushort4* orow = (ushort4*)(Xbf + (size_t)token * Dq);

  float acc[Eq];
#pragma unroll
  for (int e = 0; e < Eq; e++) acc[e] = 0.f;

#pragma unroll
  for (int it = 0; it < Dq / 256; it++) {
    int d4 = it * 64 + lane;                 // float4 index within row
    float4 xv = xrow[d4];
    ushort4 o;
    o.x = f2bf(xv.x); o.y = f2bf(xv.y); o.z = f2bf(xv.z); o.w = f2bf(xv.w);
    orow[d4] = o;
    int d = d4 * 4;
#pragma unroll
    for (int e = 0; e < Eq; e++) {
      float4 wv = *(const float4*)&rwT[e * Dq + d];
      acc[e] += xv.x * wv.x + xv.y * wv.y + xv.z * wv.z + xv.w * wv.w;
    }
  }
#pragma unroll
  for (int e = 0; e < Eq; e++) {
    float v = acc[e];
#pragma unroll
    for (int off = 32; off; off >>= 1) v += __shfl_xor(v, off);
    acc[e] = v;
  }
  if (lane == 0) {
    float v1 = -1e30f, v2 = -1e30f; int i1 = 0, i2 = 0;
#pragma unroll
    for (int e = 0; e < Eq; e++) {
      float v = acc[e] + rb[e];
      if (v > v1)      { v2 = v1; i2 = i1; v1 = v; i1 = e; }
      else if (v > v2) { v2 = v;  i2 = e; }
    }
    float ex = expf(v2 - v1);
    float wa = 1.f / (1.f + ex);
    float wb = ex / (1.f + ex);
    tok_seg[token] = i1 | ((8 + i2) << 8);   // rank0 seg, rank1 seg
    tok_w[token] = make_float2(wa, wb);
  }
}

// ---------------- segment-list build, block-aggregated atomics.
// 64 blocks x 256 tokens; 16 global atomics per block (64 per address).
__global__ __launch_bounds__(256) void scatter_build(
    const int* __restrict__ tok_seg, const float2* __restrict__ tok_w,
    int* __restrict__ cnt, int* __restrict__ seg_tok, float* __restrict__ seg_wgt)
{
  __shared__ int histA[16], histB[16], base[16];
  int t = threadIdx.x;
  if (t < 16) { histA[t] = 0; histB[t] = 0; }
  __syncthreads();
  int token = blockIdx.x * 256 + t;
  int sp = tok_seg[token];
  float2 wv = tok_w[token];
  int s0 = sp & 0xff, s1 = sp >> 8;
  atomicAdd(&histA[s0], 1);
  atomicAdd(&histA[s1], 1);
  __syncthreads();
  if (t < 16) base[t] = atomicAdd(&cnt[t], histA[t]);
  __syncthreads();
  int p0 = base[s0] + atomicAdd(&histB[s0], 1);
  seg_tok[(size_t)s0 * Mq + p0] = token;
  seg_wgt[(size_t)s0 * Mq + p0] = wv.x;
  int p1 = base[s1] + atomicAdd(&histB[s1], 1);
  seg_tok[(size_t)s1 * Mq + p1] = token;
  seg_wgt[(size_t)s1 * Mq + p1] = wv.y;
}

// ---------------- tile prefix over 16 segments (1 thread)
__global__ void prefix_kernel(const int* __restrict__ cnt, int* __restrict__ prefix)
{
  if (threadIdx.x == 0 && blockIdx.x == 0) {
    int t = 0;
#pragma unroll
    for (int s = 0; s < 16; s++) { prefix[s] = t; t += (cnt[s] + 127) >> 7; }
    prefix[16] = t;
  }
}

// ---------------- transpose+convert: in[R][C] f32 -> out[C][R] bf16, per expert z
__global__ __launch_bounds__(256) void transpose_cvt(
    const float* __restrict__ in, u16* __restrict__ out, int R, int C)
{
  __shared__ float tile[32][33];
  int e = blockIdx.z;
  in  += (size_t)e * R * C;
  out += (size_t)e * R * C;
  int c0 = blockIdx.x * 32, r0 = blockIdx.y * 32;
  int tx = threadIdx.x & 31, ty = threadIdx.x >> 5;   // ty 0..7
#pragma unroll
  for (int rr = 0; rr < 32; rr += 8)
    tile[rr + ty][tx] = in[(size_t)(r0 + rr + ty) * C + c0 + tx];
  __syncthreads();
#pragma unroll
  for (int rr = 0; rr < 32; rr += 8)
    out[(size_t)(c0 + rr + ty) * R + r0 + tx] = f2bf(tile[tx][rr + ty]);
}

// ---------------- grouped bf16 GEMM over padded 128-row tiles
// GRID: blockIdx.x = n-panel (FAST), blockIdx.y = tile.
// LDS staging is bank-conflict-swizzled BOTH-sides (rule 21): global source
// chunk index is XOR'd with (row>>1)&3, LDS dst stays linear (gload_lds),
// fragment ds_read applies the matching XOR.
// EPI 0 (GEMM1): A = Xbf[M][D] gathered via seg_tok; B = W1T[e][H][D];
//                Hout[localslot][Hq] = bf16(gelu(acc + b1[e][c]))
// EPI 1 (GEMM2): A = Hbuf[localslot][Hq]; B = W2T[e][O][H];
//                out[token][c] += (acc + b2[e][c]) * w   (HW f32 atomic,
//                out pre-zeroed; 2 commutative adds/element -> deterministic)
template<int EPI>
__global__ __launch_bounds__(256) void moe_gemm(
    const u16* __restrict__ A, const u16* __restrict__ W,
    const float* __restrict__ bias,
    u16* __restrict__ Hout, float* __restrict__ out,
    const int* __restrict__ cnt, const int* __restrict__ prefix,
    const int* __restrict__ seg_tok, const float* __restrict__ seg_wgt,
    int K, int N, int tile_lo)
{
  const int t = tile_lo + (int)blockIdx.y;
  const int total = prefix[16];
  if (t >= total) return;
  int seg = 0;
#pragma unroll
  for (int s = 1; s < 16; s++) if (prefix[s] <= t) seg = s;
  const int e = seg & 7;
  const int segcnt = cnt[seg];
  const int ti = t - prefix[seg];       // tile within segment
  const int lt = t - tile_lo;           // local tile (Hbuf)

  __shared__ u16 As[128 * 32];
  __shared__ u16 Bs[128 * 32];
  const int tid  = threadIdx.x;
  const int lane = tid & 63;
  const int wid  = tid >> 6;
  const int wr   = wid >> 1, wc = wid & 1;
  const int lrow = lane & 15, kgrp = lane >> 4;
  const int kx   = kgrp ^ ((lrow >> 1) & 3);   // swizzled read chunk
  const int n0 = blockIdx.x * 128;

  f32x4 acc[4][4];
#pragma unroll
  for (int m = 0; m < 4; m++)
#pragma unroll
    for (int n = 0; n < 4; n++) acc[m][n] = (f32x4){0.f, 0.f, 0.f, 0.f};

  // staging: thread stages rows r0 and r0+64; source k-chunk is swizzled by row
  const int r0 = tid >> 2;
  const int kc = (((tid & 3) ^ ((tid >> 3) & 3)) * 8);
  const u16 *gA0, *gA1;
  if (EPI == 0) {
    int i0 = ti * 128 + r0, i1 = i0 + 64;
    int tok0 = (i0 < segcnt) ? seg_tok[(size_t)seg * Mq + i0] : 0;
    int tok1 = (i1 < segcnt) ? seg_tok[(size_t)seg * Mq + i1] : 0;
    gA0 = A + (size_t)tok0 * K + kc;
    gA1 = A + (size_t)tok1 * K + kc;
  } else {
    gA0 = A + (size_t)(lt * 128 + r0) * K + kc;
    gA1 = gA0 + (size_t)64 * K;
  }
  const u16* gB = W + (size_t)e * K * N + (size_t)(n0 + r0) * K + kc;
  u16* lA = &As[tid * 8];
  u16* lB = &Bs[tid * 8];
  const size_t rowskipB = (size_t)64 * K;

  for (int k0 = 0; k0 < K; k0 += 32) {
    gload16(gA0, lA);
    gload16(gA1, lA + 2048);
    gload16(gB,            lB);
    gload16(gB + rowskipB, lB + 2048);
    gA0 += 32; gA1 += 32; gB += 32;
    __syncthreads();
    bf16x8 a[4], b[4];
#pragma unroll
    for (int m = 0; m < 4; m++)
      a[m] = *(const bf16x8*)&As[(wr * 64 + m * 16 + lrow) * 32 + kx * 8];
#pragma unroll
    for (int n = 0; n < 4; n++)
      b[n] = *(const bf16x8*)&Bs[(wc * 64 + n * 16 + lrow) * 32 + kx * 8];
#pragma unroll
    for (int m = 0; m < 4; m++)
#pragma unroll
      for (int n = 0; n < 4; n++)
        acc[m][n] = __builtin_amdgcn_mfma_f32_16x16x32_bf16(a[m], b[n], acc[m][n], 0, 0, 0);
    __syncthreads();
  }

  const int rbase = wr * 64;
  const int cbase = n0 + wc * 64;
  if (EPI == 0) {
#pragma unroll
    for (int n = 0; n < 4; n++) {
      int c = cbase + n * 16 + lrow;
      float bv = bias[(size_t)e * N + c];
#pragma unroll
      for (int m = 0; m < 4; m++)
#pragma unroll
        for (int j = 0; j < 4; j++) {
          int r = rbase + m * 16 + kgrp * 4 + j;
          float v = acc[m][n][j] + bv;
          Hout[(size_t)(lt * 128 + r) * N + c] = f2bf(gelu_f(v));
        }
    }
  } else {
#pragma unroll
    for (int m = 0; m < 4; m++)
#pragma unroll
      for (int j = 0; j < 4; j++) {
        int r = rbase + m * 16 + kgrp * 4 + j;
        int i = ti * 128 + r;
        if (i < segcnt) {
          int token = seg_tok[(size_t)seg * Mq + i];
          float w = seg_wgt[(size_t)seg * Mq + i];
          float* orow = out + (size_t)token * Oq;
#pragma unroll
          for (int n = 0; n < 4; n++) {
            int c = cbase + n * 16 + lrow;
            float v = (acc[m][n][j] + bias[(size_t)e * N + c]) * w;
            unsafeAtomicAdd(&orow[c], v);
          }
        }
      }
  }
}

// ---------------- in-place LayerNorm, one wave per row
__global__ __launch_bounds__(256) void ln_kernel(
    float* __restrict__ io, const float* __restrict__ g, const float* __restrict__ b)
{
  int wid = threadIdx.x >> 6, lane = threadIdx.x & 63;
  int row = blockIdx.x * 4 + wid;
  float* p = io + (size_t)row * Oq;
  float v[Oq / 64];
  float s = 0.f;
#pragma unroll
  for (int i = 0; i < Oq / 64; i++) { v[i] = p[lane + i * 64]; s += v[i]; }
#pragma unroll
  for (int off = 32; off; off >>= 1) s += __shfl_xor(s, off);
  float mu = s * (1.0f / Oq);
  float q = 0.f;
#pragma unroll
  for (int i = 0; i < Oq / 64; i++) { float d = v[i] - mu; q += d * d; }
#pragma unroll
  for (int off = 32; off; off >>= 1) q += __shfl_xor(q, off);
  float inv = rsqrtf(q * (1.0f / Oq) + LN_EPS);
#pragma unroll
  for (int i = 0; i < Oq / 64; i++) {
    int c = lane + i * 64;
    p[c] = (v[i] - mu) * inv * g[c] + b[c];
  }
}

extern "C" void kernel_launch(void* const* d_in, const int* in_sizes, int n_in,
                              void* d_out, int out_size, void* d_ws, size_t ws_size,
                              hipStream_t stream)
{
  const float* x    = (const float*)d_in[0];
  const float* rw   = (const float*)d_in[1];
  const float* rb   = (const float*)d_in[2];
  const float* w1   = (const float*)d_in[3];
  const float* b1   = (const float*)d_in[4];
  const float* w2   = (const float*)d_in[5];
  const float* b2   = (const float*)d_in[6];
  const float* ln_g = (const float*)d_in[7];
  const float* ln_b = (const float*)d_in[8];
  float* out = (float*)d_out;

  char* ws = (char*)d_ws;
  size_t off = 0;
  auto alloc = [&](size_t bytes) {
    void* p = ws + off;
    off += (bytes + 255) & ~(size_t)255;
    return p;
  };
  int*    cnt     = (int*)alloc(16 * 4);
  int*    prefix  = (int*)alloc(17 * 4);
  int*    tok_seg = (int*)alloc((size_t)Mq * 4);
  float2* tok_w   = (float2*)alloc((size_t)Mq * 8);
  int*    seg_tok = (int*)alloc((size_t)16 * Mq * 4);
  float*  seg_wgt = (float*)alloc((size_t)16 * Mq * 4);
  u16* Xbf = (u16*)alloc((size_t)Mq * Dq * 2);
  u16* W1T = (u16*)alloc((size_t)Eq * Dq * Hq * 2);
  u16* W2T = (u16*)alloc((size_t)Eq * Hq * Oq * 2);

  size_t remain = (ws_size > off) ? ws_size - off : 0;
  size_t tile_bytes = (size_t)128 * Hq * 2;   // 768 KB per slot-tile
  long long wt = (long long)(remain / tile_bytes);
  if (wt > WT_CAP) wt = WT_CAP;   // keep Hbuf chunk L3-resident (72 MB)
  if (wt < 1) wt = 1;
  int WT = (int)wt;
  u16* Hbuf = (u16*)alloc((size_t)WT * tile_bytes);

  hipMemsetAsync(out, 0, (size_t)Mq * Oq * 4, stream);
  hipMemsetAsync(cnt, 0, 16 * 4, stream);
  router_cvt_kernel<<<Mq / 4, 256, 0, stream>>>(x, rw, rb, Xbf, tok_seg, tok_w);
  scatter_build<<<Mq / 256, 256, 0, stream>>>(tok_seg, tok_w, cnt, seg_tok, seg_wgt);
  prefix_kernel<<<1, 64, 0, stream>>>(cnt, prefix);
  transpose_cvt<<<dim3(Hq / 32, Dq / 32, Eq), 256, 0, stream>>>(w1, W1T, Dq, Hq);
  transpose_cvt<<<dim3(Oq / 32, Hq / 32, Eq), 256, 0, stream>>>(w2, W2T, Hq, Oq);

  for (int tl = 0; tl < MAX_TILES; tl += WT) {
    int gx = MAX_TILES - tl; if (gx > WT) gx = WT;
    moe_gemm<0><<<dim3(Hq / 128, gx), 256, 0, stream>>>(
        Xbf, W1T, b1, Hbuf, nullptr, cnt, prefix, seg_tok, seg_wgt,
        Dq, Hq, tl);
    moe_gemm<1><<<dim3(Oq / 128, gx), 256, 0, stream>>>(
        Hbuf, W2T, b2, nullptr, out, cnt, prefix, seg_tok, seg_wgt,
        Hq, Oq, tl);
  }
  ln_kernel<<<Mq / 4, 256, 0, stream>>>(out, ln_g, ln_b);
}